// Round 24
// baseline (1454.558 us; speedup 1.0000x reference)
//
#include <hip/hip_runtime.h>

// WeightedRGCN on MI355X. Round 24: identical to round-23 source (round 23
// hit the dead pod again — resubmitting). Changes under test vs R22 (1324us):
//  1. wcur eliminated: csr fill does pos=atomicAdd(&rp[d],1) (old value =
//     slot; rp becomes end-offsets). Main reads e0=row?rp[row-1]:0,
//     e1=rp[row]. Kills 2MB memset + wcur atomic traffic in fill.
//  2. gather d-loop unroll 2->4 (more loads in flight; VALU only 44% busy).
// No numeric change: predict absmax 0.0625.
//
// ws (ints): rp_re/fb/soc (100001 ea), rp_post (200001), psum (256),
// col_re/fb/soc/post (E ea).

#define N_USER 100000
#define N_POST 200000
#define DD 128
#define GU 3125            // 100000/32 rows per block
#define GP 6250            // 200000/32

__device__ __forceinline__ unsigned int pack2_bf16(float lo, float hi) {
    unsigned int ulo, uhi;
    __builtin_memcpy(&ulo, &lo, 4);
    __builtin_memcpy(&uhi, &hi, 4);
    unsigned int rlo = (ulo + 0x7fffu + ((ulo >> 16) & 1u)) >> 16;   // RNE
    unsigned int rhi = (uhi + 0x7fffu + ((uhi >> 16) & 1u)) >> 16;
    return (rlo & 0xffffu) | (rhi << 16);
}

// D = a.lo*b.lo + a.hi*b.hi + c   (packed bf16 dot-2, fp32 accumulate)
__device__ __forceinline__ float dot2_bf16(unsigned int a, unsigned int b, float c) {
    float r;
    asm("v_dot2_f32_bf16 %0, %1, %2, %3" : "=v"(r) : "v"(a), "v"(b), "v"(c));
    return r;
}

// -------------------------------------------------------------- CSR build ---
__global__ __launch_bounds__(256) void hist_all(
        const int* __restrict__ d0, int e0, int* __restrict__ c0,
        const int* __restrict__ d1, int e1, int* __restrict__ c1,
        const int* __restrict__ d2, int e2, int* __restrict__ c2,
        const int* __restrict__ d3, int e3, int* __restrict__ c3) {
    int i = blockIdx.x * 256 + threadIdx.x;
    int stride = gridDim.x * 256;
    int b1 = e0, b2 = e0 + e1, b3 = e0 + e1 + e2, tot = b3 + e3;
    for (int t = i; t < tot; t += stride) {
        if (t < b1)      atomicAdd(&c0[d0[t]], 1);
        else if (t < b2) atomicAdd(&c1[d1[t - b1]], 1);
        else if (t < b3) atomicAdd(&c2[d2[t - b2]], 1);
        else             atomicAdd(&c3[d3[t - b3]], 1);
    }
}

// fill: pos = atomicAdd(&rp[d],1) -> rp becomes END offsets (row d spans
// [d? rp[d-1]:0, rp[d]) after this kernel).
__global__ __launch_bounds__(256) void fill_all(
        const int* __restrict__ s0, const int* __restrict__ d0, int e0,
        int* __restrict__ r0, int* __restrict__ o0,
        const int* __restrict__ s1, const int* __restrict__ d1, int e1,
        int* __restrict__ r1, int* __restrict__ o1,
        const int* __restrict__ s2, const int* __restrict__ d2, int e2,
        int* __restrict__ r2, int* __restrict__ o2,
        const int* __restrict__ s3, const int* __restrict__ d3, int e3,
        int* __restrict__ r3, int* __restrict__ o3) {
    int i = blockIdx.x * 256 + threadIdx.x;
    int stride = gridDim.x * 256;
    int b1 = e0, b2 = e0 + e1, b3 = e0 + e1 + e2, tot = b3 + e3;
    for (int t = i; t < tot; t += stride) {
        if (t < b1)      { int e = t;      int d = d0[e]; o0[atomicAdd(&r0[d], 1)] = s0[e]; }
        else if (t < b2) { int e = t - b1; int d = d1[e]; o1[atomicAdd(&r1[d], 1)] = s1[e]; }
        else if (t < b3) { int e = t - b2; int d = d2[e]; o2[atomicAdd(&r2[d], 1)] = s2[e]; }
        else             { int e = t - b3; int d = d3[e]; o3[atomicAdd(&r3[d], 1)] = s3[e]; }
    }
}

#define SCB 256
#define SCE 16
#define SCCH (SCB * SCE)   // 4096
#define NBU 25
#define NBP 49

__device__ __forceinline__ void seg_map(int b, int* rp0, int* rp1, int* rp2,
                                        int* rp3, int* psum,
                                        int** a, int* N, int** ps, int* lb) {
    if (b < NBU)            { *a = rp0; *N = N_USER; *ps = psum;       *lb = b; }
    else if (b < 2 * NBU)   { *a = rp1; *N = N_USER; *ps = psum + 64;  *lb = b - NBU; }
    else if (b < 3 * NBU)   { *a = rp2; *N = N_USER; *ps = psum + 128; *lb = b - 2 * NBU; }
    else                    { *a = rp3; *N = N_POST; *ps = psum + 192; *lb = b - 3 * NBU; }
}

__global__ __launch_bounds__(SCB) void scan_partial_all(
        int* rp0, int* rp1, int* rp2, int* rp3, int* psum) {
    int* a; int N; int* ps; int lb;
    seg_map(blockIdx.x, rp0, rp1, rp2, rp3, psum, &a, &N, &ps, &lb);
    __shared__ int red[SCB];
    int tid = threadIdx.x;
    int i0 = lb * SCCH + tid * SCE;
    int s = 0;
#pragma unroll
    for (int j = 0; j < SCE; ++j) { int i = i0 + j; if (i < N) s += a[i]; }
    red[tid] = s;
    __syncthreads();
    for (int off = SCB / 2; off > 0; off >>= 1) {
        if (tid < off) red[tid] += red[tid + off];
        __syncthreads();
    }
    if (tid == 0) ps[lb] = red[0];
}

__global__ __launch_bounds__(1024) void scan_psum_all(int* __restrict__ psum) {
    __shared__ int t[1024];
    int tid = threadIdx.x;
    int nb = (blockIdx.x == 3) ? NBP : NBU;
    int* ps = psum + blockIdx.x * 64;
    int v = (tid < nb) ? ps[tid] : 0;
    t[tid] = v;
    __syncthreads();
    for (int off = 1; off < 1024; off <<= 1) {
        int u = (tid >= off) ? t[tid - off] : 0;
        __syncthreads();
        t[tid] += u;
        __syncthreads();
    }
    if (tid < nb) ps[tid] = t[tid] - v;   // exclusive
}

__global__ __launch_bounds__(SCB) void scan_final_all(
        int* rp0, int* rp1, int* rp2, int* rp3, int* psum,
        int E0, int E1, int E2, int E3) {
    int* a; int N; int* ps; int lb;
    seg_map(blockIdx.x, rp0, rp1, rp2, rp3, psum, &a, &N, &ps, &lb);
    int E = (blockIdx.x < NBU) ? E0 : (blockIdx.x < 2*NBU) ? E1
          : (blockIdx.x < 3*NBU) ? E2 : E3;
    __shared__ int red[SCB];
    int tid = threadIdx.x;
    int i0 = lb * SCCH + tid * SCE;
    int v[SCE];
    int s = 0;
#pragma unroll
    for (int j = 0; j < SCE; ++j) { int i = i0 + j; v[j] = (i < N) ? a[i] : 0; s += v[j]; }
    red[tid] = s;
    __syncthreads();
    for (int off = 1; off < SCB; off <<= 1) {   // inclusive Hillis-Steele
        int u = (tid >= off) ? red[tid - off] : 0;
        __syncthreads();
        red[tid] += u;
        __syncthreads();
    }
    int run = ps[lb] + red[tid] - s;
#pragma unroll
    for (int j = 0; j < SCE; ++j) { int i = i0 + j; if (i < N) a[i] = run; run += v[j]; }
    if (lb == 0 && tid == 0) a[N] = E;
}

// ------------------------------------------------------------ GEMM pieces ---
// Bt[k2][c] = (B[2k2][c], B[2k2+1][c])  -- k-pair packed, 64x128 words = 32KB
__device__ __forceinline__ void stage_Bt(const float* __restrict__ B,
                                         unsigned int* Bt, int tid) {
    for (int idx = tid; idx < 64 * 128; idx += 512) {
        int k2 = idx >> 7, c = idx & 127;
        Bt[idx] = pack2_bf16(B[(2 * k2) * 128 + c], B[(2 * k2 + 1) * 128 + c]);
    }
}
__device__ __forceinline__ void stage_Bt_comb(const float* __restrict__ W0,
                                              const float* __restrict__ W1,
                                              const float* __restrict__ W2,
                                              unsigned int* Bt, int tid) {
    for (int idx = tid; idx < 64 * 128; idx += 512) {
        int k2 = idx >> 7, c = idx & 127;
        int e0 = (2 * k2) * 128 + c, e1 = (2 * k2 + 1) * 128 + c;
        float lo = 1.75f * W0[e0] + 0.7f * W1[e0] + 0.3f * W2[e0];
        float hi = 1.75f * W0[e1] + 0.7f * W1[e1] + 0.3f * W2[e1];
        Bt[idx] = pack2_bf16(lo, hi);
    }
}

// dense 4 rows -> per-wave A tile Atw[k2=lane][r]
__device__ __forceinline__ void load_rows(const float* __restrict__ A,
                                          int base, int N, int lane,
                                          unsigned int* atw) {
    uint4 w;
    unsigned int* wp = (unsigned int*)&w;
#pragma unroll
    for (int i = 0; i < 4; ++i) {
        int row = base + i;
        float vx = 0.f, vy = 0.f;
        if (row < N) {
            float2 v = ((const float2*)(A + (size_t)row * DD))[lane];
            vx = v.x; vy = v.y;
        }
        wp[i] = pack2_bf16(vx, vy);
    }
    *reinterpret_cast<uint4*>(atw + 4 * lane) = w;
}

// CSR-mean 4 rows -> Atw[k2=lane][r]; rp holds END offsets (row r spans
// [r? rp[r-1]:0, rp[r])). Interleaved d-loop, unroll 4.
__device__ __forceinline__ void gather_rows(const float* __restrict__ x,
                                            const int* __restrict__ rp,
                                            const int* __restrict__ col, float scale,
                                            int base, int N, int lane,
                                            unsigned int* atw) {
    int s0[4], dg[4];
    int maxd = 0;
#pragma unroll
    for (int i = 0; i < 4; ++i) {
        int row = base + i;
        int e1 = (row < N) ? rp[row] : 0;
        int e0 = (row > 0 && row < N) ? rp[row - 1] : 0;
        s0[i] = e0;
        dg[i] = e1 - e0;
        maxd = max(maxd, dg[i]);
    }
    float a0[4] = {0.f, 0.f, 0.f, 0.f};
    float a1[4] = {0.f, 0.f, 0.f, 0.f};
#pragma unroll 4
    for (int d = 0; d < maxd; ++d) {
#pragma unroll
        for (int i = 0; i < 4; ++i) {
            if (d < dg[i]) {
                const float2* xr = (const float2*)(x + (size_t)col[s0[i] + d] * DD);
                float2 v = xr[lane];
                a0[i] += v.x;
                a1[i] += v.y;
            }
        }
    }
    uint4 w;
    unsigned int* wp = (unsigned int*)&w;
#pragma unroll
    for (int i = 0; i < 4; ++i) {
        float inv = scale / fmaxf((float)dg[i], 1.0f);
        wp[i] = pack2_bf16(a0[i] * inv, a1[i] * inv);
    }
    *reinterpret_cast<uint4*>(atw + 4 * lane) = w;
}

// per k2: 1 broadcast b128 + 2 b32 + 8 dot2
__device__ __forceinline__ void kloop_dot2(const unsigned int* atw,
                                           const unsigned int* Bt,
                                           int lane, float acc[4][2]) {
#pragma unroll 4
    for (int k2 = 0; k2 < 64; ++k2) {
        uint4 aw = *reinterpret_cast<const uint4*>(atw + k2 * 4);   // broadcast
        unsigned int b0 = Bt[k2 * 128 + lane];
        unsigned int b1 = Bt[k2 * 128 + 64 + lane];
        acc[0][0] = dot2_bf16(aw.x, b0, acc[0][0]);
        acc[0][1] = dot2_bf16(aw.x, b1, acc[0][1]);
        acc[1][0] = dot2_bf16(aw.y, b0, acc[1][0]);
        acc[1][1] = dot2_bf16(aw.y, b1, acc[1][1]);
        acc[2][0] = dot2_bf16(aw.z, b0, acc[2][0]);
        acc[2][1] = dot2_bf16(aw.z, b1, acc[2][1]);
        acc[3][0] = dot2_bf16(aw.w, b0, acc[3][0]);
        acc[3][1] = dot2_bf16(aw.w, b1, acc[3][1]);
    }
}

// --------------------------------------------------------- fused main bodies
__device__ void user_body(
        int blk, const float* __restrict__ xu, const float* __restrict__ xp,
        const int* __restrict__ rp_re, const int* __restrict__ col_re,
        const int* __restrict__ rp_fb, const int* __restrict__ col_fb,
        const int* __restrict__ rp_soc, const int* __restrict__ col_soc,
        const float* __restrict__ Wl_d, const float* __restrict__ Wl_a,
        const float* __restrict__ Wl_s, const float* __restrict__ WrD,
        const float* __restrict__ WrA, const float* __restrict__ WrS,
        const float* __restrict__ bD, const float* __restrict__ bA,
        const float* __restrict__ bS, float* __restrict__ out,
        unsigned int* Bt, unsigned int (*Atw)[256]) {
    int wave = threadIdx.x >> 6, lane = threadIdx.x & 63;
    int base = (blk * 8 + wave) * 4;
    float acc[4][2] = {{0.f,0.f},{0.f,0.f},{0.f,0.f},{0.f,0.f}};
    stage_Bt(Wl_d, Bt, threadIdx.x);
    __syncthreads();
    gather_rows(xp, rp_re, col_re, 1.75f, base, N_USER, lane, Atw[wave]);
    kloop_dot2(Atw[wave], Bt, lane, acc);
    __syncthreads();
    stage_Bt(Wl_a, Bt, threadIdx.x);
    __syncthreads();
    gather_rows(xp, rp_fb, col_fb, 0.7f, base, N_USER, lane, Atw[wave]);
    kloop_dot2(Atw[wave], Bt, lane, acc);
    __syncthreads();
    stage_Bt(Wl_s, Bt, threadIdx.x);
    __syncthreads();
    gather_rows(xu, rp_soc, col_soc, 0.3f, base, N_USER, lane, Atw[wave]);
    kloop_dot2(Atw[wave], Bt, lane, acc);
    __syncthreads();
    stage_Bt_comb(WrD, WrA, WrS, Bt, threadIdx.x);
    __syncthreads();
    load_rows(xu, base, N_USER, lane, Atw[wave]);
    kloop_dot2(Atw[wave], Bt, lane, acc);
    float bc0 = 1.75f*bD[lane]    + 0.7f*bA[lane]    + 0.3f*bS[lane];
    float bc1 = 1.75f*bD[lane+64] + 0.7f*bA[lane+64] + 0.3f*bS[lane+64];
#pragma unroll
    for (int i = 0; i < 4; ++i) {
        int row = base + i;
        if (row < N_USER) {
            out[(size_t)row * DD + lane]      = fmaxf(acc[i][0] + bc0, 0.f);
            out[(size_t)row * DD + lane + 64] = fmaxf(acc[i][1] + bc1, 0.f);
        }
    }
}

__device__ void post_body(
        int blk, const float* __restrict__ xu, const int* __restrict__ rp,
        const int* __restrict__ col, const float* __restrict__ xp,
        const float* __restrict__ Wl, const float* __restrict__ Wr,
        const float* __restrict__ bias, float* __restrict__ out,
        unsigned int* Bt, unsigned int (*Atw)[256]) {
    int wave = threadIdx.x >> 6, lane = threadIdx.x & 63;
    int base = (blk * 8 + wave) * 4;
    float acc[4][2] = {{0.f,0.f},{0.f,0.f},{0.f,0.f},{0.f,0.f}};
    stage_Bt(Wl, Bt, threadIdx.x);
    __syncthreads();
    gather_rows(xu, rp, col, 1.0f, base, N_POST, lane, Atw[wave]);
    kloop_dot2(Atw[wave], Bt, lane, acc);
    __syncthreads();
    stage_Bt(Wr, Bt, threadIdx.x);
    __syncthreads();
    load_rows(xp, base, N_POST, lane, Atw[wave]);
    kloop_dot2(Atw[wave], Bt, lane, acc);
    float b0 = bias[lane], b1 = bias[lane + 64];
#pragma unroll
    for (int i = 0; i < 4; ++i) {
        int row = base + i;
        if (row < N_POST) {
            out[(size_t)row * DD + lane]      = fmaxf(acc[i][0] + b0, 0.f);
            out[(size_t)row * DD + lane + 64] = fmaxf(acc[i][1] + b1, 0.f);
        }
    }
}

// user blocks [0, GU), post blocks [GU, GU+GP)
__global__ __launch_bounds__(512) void main_fused_kernel(
        const float* __restrict__ xu, const float* __restrict__ xp,
        const int* __restrict__ rp_re, const int* __restrict__ col_re,
        const int* __restrict__ rp_fb, const int* __restrict__ col_fb,
        const int* __restrict__ rp_soc, const int* __restrict__ col_soc,
        const int* __restrict__ rp_post, const int* __restrict__ col_post,
        const float* __restrict__ Wl_d, const float* __restrict__ Wl_a,
        const float* __restrict__ Wl_s, const float* __restrict__ WrD,
        const float* __restrict__ WrA, const float* __restrict__ WrS,
        const float* __restrict__ bD, const float* __restrict__ bA,
        const float* __restrict__ bS, const float* __restrict__ Wl_p,
        const float* __restrict__ Wr_p, const float* __restrict__ bl_p,
        float* __restrict__ out_user, float* __restrict__ out_post) {
    __shared__ unsigned int Bt[64 * 128];        // 32 KB
    __shared__ unsigned int Atw[8][256];         // 8 KB -> 40 KB, 4 blk/CU
    if (blockIdx.x < GU) {
        user_body(blockIdx.x, xu, xp, rp_re, col_re, rp_fb, col_fb,
                  rp_soc, col_soc, Wl_d, Wl_a, Wl_s, WrD, WrA, WrS,
                  bD, bA, bS, out_user, Bt, Atw);
    } else {
        post_body(blockIdx.x - GU, xu, rp_post, col_post, xp,
                  Wl_p, Wr_p, bl_p, out_post, Bt, Atw);
    }
}

// ------------------------------------------------------------------ launch --
extern "C" void kernel_launch(void* const* d_in, const int* in_sizes, int n_in,
                              void* d_out, int out_size, void* d_ws, size_t ws_size,
                              hipStream_t stream) {
    const float* x_user  = (const float*)d_in[0];
    const float* x_post  = (const float*)d_in[1];
    const int*   re_src  = (const int*)d_in[2];
    const int*   re_dst  = (const int*)d_in[3];
    const int*   fb_src  = (const int*)d_in[4];
    const int*   fb_dst  = (const int*)d_in[5];
    const int*   soc_src = (const int*)d_in[6];
    const int*   soc_dst = (const int*)d_in[7];
    const int*   eng_src = (const int*)d_in[8];
    const int*   eng_dst = (const int*)d_in[9];
    const float* Wl_d = (const float*)d_in[10];
    const float* bl_d = (const float*)d_in[11];
    const float* Wr_d = (const float*)d_in[12];
    const float* Wl_a = (const float*)d_in[13];
    const float* bl_a = (const float*)d_in[14];
    const float* Wr_a = (const float*)d_in[15];
    const float* Wl_s = (const float*)d_in[16];
    const float* bl_s = (const float*)d_in[17];
    const float* Wr_s = (const float*)d_in[18];
    const float* Wl_p = (const float*)d_in[19];
    const float* bl_p = (const float*)d_in[20];
    const float* Wr_p = (const float*)d_in[21];

    const int E_re  = in_sizes[2];
    const int E_fb  = in_sizes[4];
    const int E_soc = in_sizes[6];
    const int E_eng = in_sizes[8];

    int* ib = (int*)d_ws;
    int* rp_re    = ib;
    int* rp_fb    = rp_re   + (N_USER + 1);
    int* rp_soc   = rp_fb   + (N_USER + 1);
    int* rp_post  = rp_soc  + (N_USER + 1);
    int* psum     = rp_post + (N_POST + 1);  // 4 x 64 slices
    int* col_re   = psum + 256;
    int* col_fb   = col_re  + E_re;
    int* col_soc  = col_fb  + E_fb;
    int* col_post = col_soc + E_soc;

    float* out_user = (float*)d_out;
    float* out_post = out_user + (size_t)N_USER * DD;

    // one memset over rp arrays + psum (contiguous)
    size_t zero_ints = (size_t)(N_USER + 1) * 3 + (N_POST + 1) + 256;
    hipMemsetAsync(rp_re, 0, zero_ints * sizeof(int), stream);

    hist_all<<<2048, 256, 0, stream>>>(re_dst, E_re, rp_re,
                                       fb_dst, E_fb, rp_fb,
                                       soc_dst, E_soc, rp_soc,
                                       eng_dst, E_eng, rp_post);

    const int SC_BLOCKS_ALL = 3 * NBU + NBP;   // 124
    scan_partial_all<<<SC_BLOCKS_ALL, SCB, 0, stream>>>(rp_re, rp_fb, rp_soc,
                                                        rp_post, psum);
    scan_psum_all<<<4, 1024, 0, stream>>>(psum);
    scan_final_all<<<SC_BLOCKS_ALL, SCB, 0, stream>>>(rp_re, rp_fb, rp_soc,
                                                      rp_post, psum,
                                                      E_re, E_fb, E_soc, E_eng);

    // fill transforms rp -> end offsets (atomicAdd returns slot)
    fill_all<<<2048, 256, 0, stream>>>(
        re_src,  re_dst,  E_re,  rp_re,   col_re,
        fb_src,  fb_dst,  E_fb,  rp_fb,   col_fb,
        soc_src, soc_dst, E_soc, rp_soc,  col_soc,
        eng_src, eng_dst, E_eng, rp_post, col_post);

    main_fused_kernel<<<GU + GP, 512, 0, stream>>>(
        x_user, x_post, rp_re, col_re, rp_fb, col_fb, rp_soc, col_soc,
        rp_post, col_post, Wl_d, Wl_a, Wl_s, Wr_d, Wr_a, Wr_s,
        bl_d, bl_a, bl_s, Wl_p, Wr_p, bl_p, out_user, out_post);
}

// Round 25
// 1324.158 us; speedup vs baseline: 1.0985x; 1.0985x over previous
//
#include <hip/hip_runtime.h>

// WeightedRGCN on MI355X. Round 25: R22 VERBATIM (best measured: 1324us).
// R24's A/B proved: unroll-4 gather neutral (main_fused 878us identical),
// wcur-elimination REGRESSED fill (+130us: returning atomics on rp lines
// replaced cacheable read-only rp loads + separate wcur atomics). Revert.
//
// ws (ints): rp_re/fb/soc (100001 ea), rp_post (200001), wcur x4, psum(256),
// col_re/fb/soc/post.

#define N_USER 100000
#define N_POST 200000
#define DD 128
#define GU 3125            // 100000/32 rows per block
#define GP 6250            // 200000/32

__device__ __forceinline__ unsigned int pack2_bf16(float lo, float hi) {
    unsigned int ulo, uhi;
    __builtin_memcpy(&ulo, &lo, 4);
    __builtin_memcpy(&uhi, &hi, 4);
    unsigned int rlo = (ulo + 0x7fffu + ((ulo >> 16) & 1u)) >> 16;   // RNE
    unsigned int rhi = (uhi + 0x7fffu + ((uhi >> 16) & 1u)) >> 16;
    return (rlo & 0xffffu) | (rhi << 16);
}

// D = a.lo*b.lo + a.hi*b.hi + c   (packed bf16 dot-2, fp32 accumulate)
__device__ __forceinline__ float dot2_bf16(unsigned int a, unsigned int b, float c) {
    float r;
    asm("v_dot2_f32_bf16 %0, %1, %2, %3" : "=v"(r) : "v"(a), "v"(b), "v"(c));
    return r;
}

// -------------------------------------------------------------- CSR build ---
__global__ __launch_bounds__(256) void hist_all(
        const int* __restrict__ d0, int e0, int* __restrict__ c0,
        const int* __restrict__ d1, int e1, int* __restrict__ c1,
        const int* __restrict__ d2, int e2, int* __restrict__ c2,
        const int* __restrict__ d3, int e3, int* __restrict__ c3) {
    int i = blockIdx.x * 256 + threadIdx.x;
    int stride = gridDim.x * 256;
    int b1 = e0, b2 = e0 + e1, b3 = e0 + e1 + e2, tot = b3 + e3;
    for (int t = i; t < tot; t += stride) {
        if (t < b1)      atomicAdd(&c0[d0[t]], 1);
        else if (t < b2) atomicAdd(&c1[d1[t - b1]], 1);
        else if (t < b3) atomicAdd(&c2[d2[t - b2]], 1);
        else             atomicAdd(&c3[d3[t - b3]], 1);
    }
}

__global__ __launch_bounds__(256) void fill_all(
        const int* __restrict__ s0, const int* __restrict__ d0, int e0,
        const int* __restrict__ r0, int* __restrict__ w0, int* __restrict__ o0,
        const int* __restrict__ s1, const int* __restrict__ d1, int e1,
        const int* __restrict__ r1, int* __restrict__ w1, int* __restrict__ o1,
        const int* __restrict__ s2, const int* __restrict__ d2, int e2,
        const int* __restrict__ r2, int* __restrict__ w2, int* __restrict__ o2,
        const int* __restrict__ s3, const int* __restrict__ d3, int e3,
        const int* __restrict__ r3, int* __restrict__ w3, int* __restrict__ o3) {
    int i = blockIdx.x * 256 + threadIdx.x;
    int stride = gridDim.x * 256;
    int b1 = e0, b2 = e0 + e1, b3 = e0 + e1 + e2, tot = b3 + e3;
    for (int t = i; t < tot; t += stride) {
        if (t < b1)      { int e = t;      int d = d0[e]; o0[r0[d] + atomicAdd(&w0[d], 1)] = s0[e]; }
        else if (t < b2) { int e = t - b1; int d = d1[e]; o1[r1[d] + atomicAdd(&w1[d], 1)] = s1[e]; }
        else if (t < b3) { int e = t - b2; int d = d2[e]; o2[r2[d] + atomicAdd(&w2[d], 1)] = s2[e]; }
        else             { int e = t - b3; int d = d3[e]; o3[r3[d] + atomicAdd(&w3[d], 1)] = s3[e]; }
    }
}

#define SCB 256
#define SCE 16
#define SCCH (SCB * SCE)   // 4096
#define NBU 25
#define NBP 49

__device__ __forceinline__ void seg_map(int b, int* rp0, int* rp1, int* rp2,
                                        int* rp3, int* psum,
                                        int** a, int* N, int** ps, int* lb) {
    if (b < NBU)            { *a = rp0; *N = N_USER; *ps = psum;       *lb = b; }
    else if (b < 2 * NBU)   { *a = rp1; *N = N_USER; *ps = psum + 64;  *lb = b - NBU; }
    else if (b < 3 * NBU)   { *a = rp2; *N = N_USER; *ps = psum + 128; *lb = b - 2 * NBU; }
    else                    { *a = rp3; *N = N_POST; *ps = psum + 192; *lb = b - 3 * NBU; }
}

__global__ __launch_bounds__(SCB) void scan_partial_all(
        int* rp0, int* rp1, int* rp2, int* rp3, int* psum) {
    int* a; int N; int* ps; int lb;
    seg_map(blockIdx.x, rp0, rp1, rp2, rp3, psum, &a, &N, &ps, &lb);
    __shared__ int red[SCB];
    int tid = threadIdx.x;
    int i0 = lb * SCCH + tid * SCE;
    int s = 0;
#pragma unroll
    for (int j = 0; j < SCE; ++j) { int i = i0 + j; if (i < N) s += a[i]; }
    red[tid] = s;
    __syncthreads();
    for (int off = SCB / 2; off > 0; off >>= 1) {
        if (tid < off) red[tid] += red[tid + off];
        __syncthreads();
    }
    if (tid == 0) ps[lb] = red[0];
}

__global__ __launch_bounds__(1024) void scan_psum_all(int* __restrict__ psum) {
    __shared__ int t[1024];
    int tid = threadIdx.x;
    int nb = (blockIdx.x == 3) ? NBP : NBU;
    int* ps = psum + blockIdx.x * 64;
    int v = (tid < nb) ? ps[tid] : 0;
    t[tid] = v;
    __syncthreads();
    for (int off = 1; off < 1024; off <<= 1) {
        int u = (tid >= off) ? t[tid - off] : 0;
        __syncthreads();
        t[tid] += u;
        __syncthreads();
    }
    if (tid < nb) ps[tid] = t[tid] - v;   // exclusive
}

__global__ __launch_bounds__(SCB) void scan_final_all(
        int* rp0, int* rp1, int* rp2, int* rp3, int* psum,
        int E0, int E1, int E2, int E3) {
    int* a; int N; int* ps; int lb;
    seg_map(blockIdx.x, rp0, rp1, rp2, rp3, psum, &a, &N, &ps, &lb);
    int E = (blockIdx.x < NBU) ? E0 : (blockIdx.x < 2*NBU) ? E1
          : (blockIdx.x < 3*NBU) ? E2 : E3;
    __shared__ int red[SCB];
    int tid = threadIdx.x;
    int i0 = lb * SCCH + tid * SCE;
    int v[SCE];
    int s = 0;
#pragma unroll
    for (int j = 0; j < SCE; ++j) { int i = i0 + j; v[j] = (i < N) ? a[i] : 0; s += v[j]; }
    red[tid] = s;
    __syncthreads();
    for (int off = 1; off < SCB; off <<= 1) {   // inclusive Hillis-Steele
        int u = (tid >= off) ? red[tid - off] : 0;
        __syncthreads();
        red[tid] += u;
        __syncthreads();
    }
    int run = ps[lb] + red[tid] - s;
#pragma unroll
    for (int j = 0; j < SCE; ++j) { int i = i0 + j; if (i < N) a[i] = run; run += v[j]; }
    if (lb == 0 && tid == 0) a[N] = E;
}

// ------------------------------------------------------------ GEMM pieces ---
// Bt[k2][c] = (B[2k2][c], B[2k2+1][c])  -- k-pair packed, 64x128 words = 32KB
__device__ __forceinline__ void stage_Bt(const float* __restrict__ B,
                                         unsigned int* Bt, int tid) {
    for (int idx = tid; idx < 64 * 128; idx += 512) {
        int k2 = idx >> 7, c = idx & 127;
        Bt[idx] = pack2_bf16(B[(2 * k2) * 128 + c], B[(2 * k2 + 1) * 128 + c]);
    }
}
__device__ __forceinline__ void stage_Bt_comb(const float* __restrict__ W0,
                                              const float* __restrict__ W1,
                                              const float* __restrict__ W2,
                                              unsigned int* Bt, int tid) {
    for (int idx = tid; idx < 64 * 128; idx += 512) {
        int k2 = idx >> 7, c = idx & 127;
        int e0 = (2 * k2) * 128 + c, e1 = (2 * k2 + 1) * 128 + c;
        float lo = 1.75f * W0[e0] + 0.7f * W1[e0] + 0.3f * W2[e0];
        float hi = 1.75f * W0[e1] + 0.7f * W1[e1] + 0.3f * W2[e1];
        Bt[idx] = pack2_bf16(lo, hi);
    }
}

// dense 4 rows -> per-wave A tile Atw[k2=lane][r]
__device__ __forceinline__ void load_rows(const float* __restrict__ A,
                                          int base, int N, int lane,
                                          unsigned int* atw) {
    uint4 w;
    unsigned int* wp = (unsigned int*)&w;
#pragma unroll
    for (int i = 0; i < 4; ++i) {
        int row = base + i;
        float vx = 0.f, vy = 0.f;
        if (row < N) {
            float2 v = ((const float2*)(A + (size_t)row * DD))[lane];
            vx = v.x; vy = v.y;
        }
        wp[i] = pack2_bf16(vx, vy);
    }
    *reinterpret_cast<uint4*>(atw + 4 * lane) = w;   // Atw[k2=lane][0..3]
}

// CSR-mean 4 rows (R16-proven interleave) -> Atw[k2=lane][r]
__device__ __forceinline__ void gather_rows(const float* __restrict__ x,
                                            const int* __restrict__ rp,
                                            const int* __restrict__ col, float scale,
                                            int base, int N, int lane,
                                            unsigned int* atw) {
    int s0[4], dg[4];
    int maxd = 0;
#pragma unroll
    for (int i = 0; i < 4; ++i) {
        int row = base + i;
        int e0 = (row < N) ? rp[row] : 0;
        int e1 = (row < N) ? rp[row + 1] : 0;
        s0[i] = e0;
        dg[i] = e1 - e0;
        maxd = max(maxd, dg[i]);
    }
    float a0[4] = {0.f, 0.f, 0.f, 0.f};
    float a1[4] = {0.f, 0.f, 0.f, 0.f};
#pragma unroll 2
    for (int d = 0; d < maxd; ++d) {
#pragma unroll
        for (int i = 0; i < 4; ++i) {
            if (d < dg[i]) {
                const float2* xr = (const float2*)(x + (size_t)col[s0[i] + d] * DD);
                float2 v = xr[lane];
                a0[i] += v.x;
                a1[i] += v.y;
            }
        }
    }
    uint4 w;
    unsigned int* wp = (unsigned int*)&w;
#pragma unroll
    for (int i = 0; i < 4; ++i) {
        float inv = scale / fmaxf((float)dg[i], 1.0f);
        wp[i] = pack2_bf16(a0[i] * inv, a1[i] * inv);
    }
    *reinterpret_cast<uint4*>(atw + 4 * lane) = w;
}

// per k2: 1 broadcast b128 (A rows 0..3) + 2 b32 (B cols lane, lane+64)
// + 8 dot2. acc[i][0]=col lane, acc[i][1]=col lane+64.
__device__ __forceinline__ void kloop_dot2(const unsigned int* atw,
                                           const unsigned int* Bt,
                                           int lane, float acc[4][2]) {
#pragma unroll 4
    for (int k2 = 0; k2 < 64; ++k2) {
        uint4 aw = *reinterpret_cast<const uint4*>(atw + k2 * 4);   // broadcast
        unsigned int b0 = Bt[k2 * 128 + lane];
        unsigned int b1 = Bt[k2 * 128 + 64 + lane];
        acc[0][0] = dot2_bf16(aw.x, b0, acc[0][0]);
        acc[0][1] = dot2_bf16(aw.x, b1, acc[0][1]);
        acc[1][0] = dot2_bf16(aw.y, b0, acc[1][0]);
        acc[1][1] = dot2_bf16(aw.y, b1, acc[1][1]);
        acc[2][0] = dot2_bf16(aw.z, b0, acc[2][0]);
        acc[2][1] = dot2_bf16(aw.z, b1, acc[2][1]);
        acc[3][0] = dot2_bf16(aw.w, b0, acc[3][0]);
        acc[3][1] = dot2_bf16(aw.w, b1, acc[3][1]);
    }
}

// --------------------------------------------------------- fused main bodies
__device__ void user_body(
        int blk, const float* __restrict__ xu, const float* __restrict__ xp,
        const int* __restrict__ rp_re, const int* __restrict__ col_re,
        const int* __restrict__ rp_fb, const int* __restrict__ col_fb,
        const int* __restrict__ rp_soc, const int* __restrict__ col_soc,
        const float* __restrict__ Wl_d, const float* __restrict__ Wl_a,
        const float* __restrict__ Wl_s, const float* __restrict__ WrD,
        const float* __restrict__ WrA, const float* __restrict__ WrS,
        const float* __restrict__ bD, const float* __restrict__ bA,
        const float* __restrict__ bS, float* __restrict__ out,
        unsigned int* Bt, unsigned int (*Atw)[256]) {
    int wave = threadIdx.x >> 6, lane = threadIdx.x & 63;
    int base = (blk * 8 + wave) * 4;
    float acc[4][2] = {{0.f,0.f},{0.f,0.f},{0.f,0.f},{0.f,0.f}};
    stage_Bt(Wl_d, Bt, threadIdx.x);
    __syncthreads();
    gather_rows(xp, rp_re, col_re, 1.75f, base, N_USER, lane, Atw[wave]);
    kloop_dot2(Atw[wave], Bt, lane, acc);
    __syncthreads();
    stage_Bt(Wl_a, Bt, threadIdx.x);
    __syncthreads();
    gather_rows(xp, rp_fb, col_fb, 0.7f, base, N_USER, lane, Atw[wave]);
    kloop_dot2(Atw[wave], Bt, lane, acc);
    __syncthreads();
    stage_Bt(Wl_s, Bt, threadIdx.x);
    __syncthreads();
    gather_rows(xu, rp_soc, col_soc, 0.3f, base, N_USER, lane, Atw[wave]);
    kloop_dot2(Atw[wave], Bt, lane, acc);
    __syncthreads();
    stage_Bt_comb(WrD, WrA, WrS, Bt, threadIdx.x);
    __syncthreads();
    load_rows(xu, base, N_USER, lane, Atw[wave]);
    kloop_dot2(Atw[wave], Bt, lane, acc);
    float bc0 = 1.75f*bD[lane]    + 0.7f*bA[lane]    + 0.3f*bS[lane];
    float bc1 = 1.75f*bD[lane+64] + 0.7f*bA[lane+64] + 0.3f*bS[lane+64];
#pragma unroll
    for (int i = 0; i < 4; ++i) {
        int row = base + i;
        if (row < N_USER) {
            out[(size_t)row * DD + lane]      = fmaxf(acc[i][0] + bc0, 0.f);
            out[(size_t)row * DD + lane + 64] = fmaxf(acc[i][1] + bc1, 0.f);
        }
    }
}

__device__ void post_body(
        int blk, const float* __restrict__ xu, const int* __restrict__ rp,
        const int* __restrict__ col, const float* __restrict__ xp,
        const float* __restrict__ Wl, const float* __restrict__ Wr,
        const float* __restrict__ bias, float* __restrict__ out,
        unsigned int* Bt, unsigned int (*Atw)[256]) {
    int wave = threadIdx.x >> 6, lane = threadIdx.x & 63;
    int base = (blk * 8 + wave) * 4;
    float acc[4][2] = {{0.f,0.f},{0.f,0.f},{0.f,0.f},{0.f,0.f}};
    stage_Bt(Wl, Bt, threadIdx.x);
    __syncthreads();
    gather_rows(xu, rp, col, 1.0f, base, N_POST, lane, Atw[wave]);
    kloop_dot2(Atw[wave], Bt, lane, acc);
    __syncthreads();
    stage_Bt(Wr, Bt, threadIdx.x);
    __syncthreads();
    load_rows(xp, base, N_POST, lane, Atw[wave]);
    kloop_dot2(Atw[wave], Bt, lane, acc);
    float b0 = bias[lane], b1 = bias[lane + 64];
#pragma unroll
    for (int i = 0; i < 4; ++i) {
        int row = base + i;
        if (row < N_POST) {
            out[(size_t)row * DD + lane]      = fmaxf(acc[i][0] + b0, 0.f);
            out[(size_t)row * DD + lane + 64] = fmaxf(acc[i][1] + b1, 0.f);
        }
    }
}

// user blocks [0, GU), post blocks [GU, GU+GP)
__global__ __launch_bounds__(512) void main_fused_kernel(
        const float* __restrict__ xu, const float* __restrict__ xp,
        const int* __restrict__ rp_re, const int* __restrict__ col_re,
        const int* __restrict__ rp_fb, const int* __restrict__ col_fb,
        const int* __restrict__ rp_soc, const int* __restrict__ col_soc,
        const int* __restrict__ rp_post, const int* __restrict__ col_post,
        const float* __restrict__ Wl_d, const float* __restrict__ Wl_a,
        const float* __restrict__ Wl_s, const float* __restrict__ WrD,
        const float* __restrict__ WrA, const float* __restrict__ WrS,
        const float* __restrict__ bD, const float* __restrict__ bA,
        const float* __restrict__ bS, const float* __restrict__ Wl_p,
        const float* __restrict__ Wr_p, const float* __restrict__ bl_p,
        float* __restrict__ out_user, float* __restrict__ out_post) {
    __shared__ unsigned int Bt[64 * 128];        // 32 KB
    __shared__ unsigned int Atw[8][256];         // 8 KB -> 40 KB, 4 blk/CU
    if (blockIdx.x < GU) {
        user_body(blockIdx.x, xu, xp, rp_re, col_re, rp_fb, col_fb,
                  rp_soc, col_soc, Wl_d, Wl_a, Wl_s, WrD, WrA, WrS,
                  bD, bA, bS, out_user, Bt, Atw);
    } else {
        post_body(blockIdx.x - GU, xu, rp_post, col_post, xp,
                  Wl_p, Wr_p, bl_p, out_post, Bt, Atw);
    }
}

// ------------------------------------------------------------------ launch --
extern "C" void kernel_launch(void* const* d_in, const int* in_sizes, int n_in,
                              void* d_out, int out_size, void* d_ws, size_t ws_size,
                              hipStream_t stream) {
    const float* x_user  = (const float*)d_in[0];
    const float* x_post  = (const float*)d_in[1];
    const int*   re_src  = (const int*)d_in[2];
    const int*   re_dst  = (const int*)d_in[3];
    const int*   fb_src  = (const int*)d_in[4];
    const int*   fb_dst  = (const int*)d_in[5];
    const int*   soc_src = (const int*)d_in[6];
    const int*   soc_dst = (const int*)d_in[7];
    const int*   eng_src = (const int*)d_in[8];
    const int*   eng_dst = (const int*)d_in[9];
    const float* Wl_d = (const float*)d_in[10];
    const float* bl_d = (const float*)d_in[11];
    const float* Wr_d = (const float*)d_in[12];
    const float* Wl_a = (const float*)d_in[13];
    const float* bl_a = (const float*)d_in[14];
    const float* Wr_a = (const float*)d_in[15];
    const float* Wl_s = (const float*)d_in[16];
    const float* bl_s = (const float*)d_in[17];
    const float* Wr_s = (const float*)d_in[18];
    const float* Wl_p = (const float*)d_in[19];
    const float* bl_p = (const float*)d_in[20];
    const float* Wr_p = (const float*)d_in[21];

    const int E_re  = in_sizes[2];
    const int E_fb  = in_sizes[4];
    const int E_soc = in_sizes[6];
    const int E_eng = in_sizes[8];

    int* ib = (int*)d_ws;
    int* rp_re    = ib;
    int* rp_fb    = rp_re   + (N_USER + 1);
    int* rp_soc   = rp_fb   + (N_USER + 1);
    int* rp_post  = rp_soc  + (N_USER + 1);
    int* wcur_re  = rp_post + (N_POST + 1);
    int* wcur_fb  = wcur_re + N_USER;
    int* wcur_soc = wcur_fb + N_USER;
    int* wcur_post= wcur_soc+ N_USER;
    int* psum     = wcur_post + N_POST;      // 4 x 64 slices
    int* col_re   = psum + 256;
    int* col_fb   = col_re  + E_re;
    int* col_soc  = col_fb  + E_fb;
    int* col_post = col_soc + E_soc;

    float* out_user = (float*)d_out;
    float* out_post = out_user + (size_t)N_USER * DD;

    // one memset over rp + wcur + psum (contiguous)
    size_t zero_ints = (size_t)(N_USER + 1) * 3 + (N_POST + 1)
                     + (size_t)N_USER * 3 + N_POST + 256;
    hipMemsetAsync(rp_re, 0, zero_ints * sizeof(int), stream);

    hist_all<<<2048, 256, 0, stream>>>(re_dst, E_re, rp_re,
                                       fb_dst, E_fb, rp_fb,
                                       soc_dst, E_soc, rp_soc,
                                       eng_dst, E_eng, rp_post);

    const int SC_BLOCKS_ALL = 3 * NBU + NBP;   // 124
    scan_partial_all<<<SC_BLOCKS_ALL, SCB, 0, stream>>>(rp_re, rp_fb, rp_soc,
                                                        rp_post, psum);
    scan_psum_all<<<4, 1024, 0, stream>>>(psum);
    scan_final_all<<<SC_BLOCKS_ALL, SCB, 0, stream>>>(rp_re, rp_fb, rp_soc,
                                                      rp_post, psum,
                                                      E_re, E_fb, E_soc, E_eng);

    fill_all<<<2048, 256, 0, stream>>>(
        re_src,  re_dst,  E_re,  rp_re,   wcur_re,   col_re,
        fb_src,  fb_dst,  E_fb,  rp_fb,   wcur_fb,   col_fb,
        soc_src, soc_dst, E_soc, rp_soc,  wcur_soc,  col_soc,
        eng_src, eng_dst, E_eng, rp_post, wcur_post, col_post);

    main_fused_kernel<<<GU + GP, 512, 0, stream>>>(
        x_user, x_post, rp_re, col_re, rp_fb, col_fb, rp_soc, col_soc,
        rp_post, col_post, Wl_d, Wl_a, Wl_s, Wr_d, Wr_a, Wr_s,
        bl_d, bl_a, bl_s, Wl_p, Wr_p, bl_p, out_user, out_post);
}

// Round 26
// 1318.415 us; speedup vs baseline: 1.1033x; 1.0044x over previous
//
#include <hip/hip_runtime.h>

// WeightedRGCN on MI355X. Round 26: R25/R22 base (1324us, best) + bf16
// feature pre-conversion: x_user/x_post converted once to bf16 in ws
// (~230MB pass ~45us), gathers read 256B/edge instead of 512B (the A-tile
// rounds to bf16 anyway - fp32 gather precision was discarded). Dense
// phases become raw uint copies. Gather traffic 3GB -> 1.5GB.
//
// ws (ints): rp x4, wcur x4, psum(256), col x4 (5.6M), xub (6.4M),
// xpb (12.8M)  => ~25.9M ints = 103.6MB.

#define N_USER 100000
#define N_POST 200000
#define DD 128
#define GU 3125            // 100000/32 rows per block
#define GP 6250            // 200000/32

__device__ __forceinline__ unsigned int pack2_bf16(float lo, float hi) {
    unsigned int ulo, uhi;
    __builtin_memcpy(&ulo, &lo, 4);
    __builtin_memcpy(&uhi, &hi, 4);
    unsigned int rlo = (ulo + 0x7fffu + ((ulo >> 16) & 1u)) >> 16;   // RNE
    unsigned int rhi = (uhi + 0x7fffu + ((uhi >> 16) & 1u)) >> 16;
    return (rlo & 0xffffu) | (rhi << 16);
}
__device__ __forceinline__ float bf16_lo(unsigned int u) {
    unsigned int t = u << 16; float f; __builtin_memcpy(&f, &t, 4); return f;
}
__device__ __forceinline__ float bf16_hi(unsigned int u) {
    unsigned int t = u & 0xffff0000u; float f; __builtin_memcpy(&f, &t, 4); return f;
}

// D = a.lo*b.lo + a.hi*b.hi + c   (packed bf16 dot-2, fp32 accumulate)
__device__ __forceinline__ float dot2_bf16(unsigned int a, unsigned int b, float c) {
    float r;
    asm("v_dot2_f32_bf16 %0, %1, %2, %3" : "=v"(r) : "v"(a), "v"(b), "v"(c));
    return r;
}

// --------------------------------------------------------- bf16 conversion --
__global__ __launch_bounds__(256) void conv_bf16(
        const float* __restrict__ xu, const float* __restrict__ xp,
        unsigned int* __restrict__ xub, unsigned int* __restrict__ xpb) {
    const int NU = N_USER * 64, NP = N_POST * 64;   // uint counts
    int i = blockIdx.x * 256 + threadIdx.x;
    int stride = gridDim.x * 256;
    for (int t = i; t < NU + NP; t += stride) {
        if (t < NU) {
            float2 v = ((const float2*)xu)[t];
            xub[t] = pack2_bf16(v.x, v.y);
        } else {
            float2 v = ((const float2*)xp)[t - NU];
            xpb[t - NU] = pack2_bf16(v.x, v.y);
        }
    }
}

// -------------------------------------------------- CSR build (R22 verbatim)
__global__ __launch_bounds__(256) void hist_all(
        const int* __restrict__ d0, int e0, int* __restrict__ c0,
        const int* __restrict__ d1, int e1, int* __restrict__ c1,
        const int* __restrict__ d2, int e2, int* __restrict__ c2,
        const int* __restrict__ d3, int e3, int* __restrict__ c3) {
    int i = blockIdx.x * 256 + threadIdx.x;
    int stride = gridDim.x * 256;
    int b1 = e0, b2 = e0 + e1, b3 = e0 + e1 + e2, tot = b3 + e3;
    for (int t = i; t < tot; t += stride) {
        if (t < b1)      atomicAdd(&c0[d0[t]], 1);
        else if (t < b2) atomicAdd(&c1[d1[t - b1]], 1);
        else if (t < b3) atomicAdd(&c2[d2[t - b2]], 1);
        else             atomicAdd(&c3[d3[t - b3]], 1);
    }
}

__global__ __launch_bounds__(256) void fill_all(
        const int* __restrict__ s0, const int* __restrict__ d0, int e0,
        const int* __restrict__ r0, int* __restrict__ w0, int* __restrict__ o0,
        const int* __restrict__ s1, const int* __restrict__ d1, int e1,
        const int* __restrict__ r1, int* __restrict__ w1, int* __restrict__ o1,
        const int* __restrict__ s2, const int* __restrict__ d2, int e2,
        const int* __restrict__ r2, int* __restrict__ w2, int* __restrict__ o2,
        const int* __restrict__ s3, const int* __restrict__ d3, int e3,
        const int* __restrict__ r3, int* __restrict__ w3, int* __restrict__ o3) {
    int i = blockIdx.x * 256 + threadIdx.x;
    int stride = gridDim.x * 256;
    int b1 = e0, b2 = e0 + e1, b3 = e0 + e1 + e2, tot = b3 + e3;
    for (int t = i; t < tot; t += stride) {
        if (t < b1)      { int e = t;      int d = d0[e]; o0[r0[d] + atomicAdd(&w0[d], 1)] = s0[e]; }
        else if (t < b2) { int e = t - b1; int d = d1[e]; o1[r1[d] + atomicAdd(&w1[d], 1)] = s1[e]; }
        else if (t < b3) { int e = t - b2; int d = d2[e]; o2[r2[d] + atomicAdd(&w2[d], 1)] = s2[e]; }
        else             { int e = t - b3; int d = d3[e]; o3[r3[d] + atomicAdd(&w3[d], 1)] = s3[e]; }
    }
}

#define SCB 256
#define SCE 16
#define SCCH (SCB * SCE)   // 4096
#define NBU 25
#define NBP 49

__device__ __forceinline__ void seg_map(int b, int* rp0, int* rp1, int* rp2,
                                        int* rp3, int* psum,
                                        int** a, int* N, int** ps, int* lb) {
    if (b < NBU)            { *a = rp0; *N = N_USER; *ps = psum;       *lb = b; }
    else if (b < 2 * NBU)   { *a = rp1; *N = N_USER; *ps = psum + 64;  *lb = b - NBU; }
    else if (b < 3 * NBU)   { *a = rp2; *N = N_USER; *ps = psum + 128; *lb = b - 2 * NBU; }
    else                    { *a = rp3; *N = N_POST; *ps = psum + 192; *lb = b - 3 * NBU; }
}

__global__ __launch_bounds__(SCB) void scan_partial_all(
        int* rp0, int* rp1, int* rp2, int* rp3, int* psum) {
    int* a; int N; int* ps; int lb;
    seg_map(blockIdx.x, rp0, rp1, rp2, rp3, psum, &a, &N, &ps, &lb);
    __shared__ int red[SCB];
    int tid = threadIdx.x;
    int i0 = lb * SCCH + tid * SCE;
    int s = 0;
#pragma unroll
    for (int j = 0; j < SCE; ++j) { int i = i0 + j; if (i < N) s += a[i]; }
    red[tid] = s;
    __syncthreads();
    for (int off = SCB / 2; off > 0; off >>= 1) {
        if (tid < off) red[tid] += red[tid + off];
        __syncthreads();
    }
    if (tid == 0) ps[lb] = red[0];
}

__global__ __launch_bounds__(1024) void scan_psum_all(int* __restrict__ psum) {
    __shared__ int t[1024];
    int tid = threadIdx.x;
    int nb = (blockIdx.x == 3) ? NBP : NBU;
    int* ps = psum + blockIdx.x * 64;
    int v = (tid < nb) ? ps[tid] : 0;
    t[tid] = v;
    __syncthreads();
    for (int off = 1; off < 1024; off <<= 1) {
        int u = (tid >= off) ? t[tid - off] : 0;
        __syncthreads();
        t[tid] += u;
        __syncthreads();
    }
    if (tid < nb) ps[tid] = t[tid] - v;   // exclusive
}

__global__ __launch_bounds__(SCB) void scan_final_all(
        int* rp0, int* rp1, int* rp2, int* rp3, int* psum,
        int E0, int E1, int E2, int E3) {
    int* a; int N; int* ps; int lb;
    seg_map(blockIdx.x, rp0, rp1, rp2, rp3, psum, &a, &N, &ps, &lb);
    int E = (blockIdx.x < NBU) ? E0 : (blockIdx.x < 2*NBU) ? E1
          : (blockIdx.x < 3*NBU) ? E2 : E3;
    __shared__ int red[SCB];
    int tid = threadIdx.x;
    int i0 = lb * SCCH + tid * SCE;
    int v[SCE];
    int s = 0;
#pragma unroll
    for (int j = 0; j < SCE; ++j) { int i = i0 + j; v[j] = (i < N) ? a[i] : 0; s += v[j]; }
    red[tid] = s;
    __syncthreads();
    for (int off = 1; off < SCB; off <<= 1) {   // inclusive Hillis-Steele
        int u = (tid >= off) ? red[tid - off] : 0;
        __syncthreads();
        red[tid] += u;
        __syncthreads();
    }
    int run = ps[lb] + red[tid] - s;
#pragma unroll
    for (int j = 0; j < SCE; ++j) { int i = i0 + j; if (i < N) a[i] = run; run += v[j]; }
    if (lb == 0 && tid == 0) a[N] = E;
}

// ------------------------------------------------------------ GEMM pieces ---
// Bt[k2][c] = (B[2k2][c], B[2k2+1][c])  -- k-pair packed, 64x128 words = 32KB
__device__ __forceinline__ void stage_Bt(const float* __restrict__ B,
                                         unsigned int* Bt, int tid) {
    for (int idx = tid; idx < 64 * 128; idx += 512) {
        int k2 = idx >> 7, c = idx & 127;
        Bt[idx] = pack2_bf16(B[(2 * k2) * 128 + c], B[(2 * k2 + 1) * 128 + c]);
    }
}
__device__ __forceinline__ void stage_Bt_comb(const float* __restrict__ W0,
                                              const float* __restrict__ W1,
                                              const float* __restrict__ W2,
                                              unsigned int* Bt, int tid) {
    for (int idx = tid; idx < 64 * 128; idx += 512) {
        int k2 = idx >> 7, c = idx & 127;
        int e0 = (2 * k2) * 128 + c, e1 = (2 * k2 + 1) * 128 + c;
        float lo = 1.75f * W0[e0] + 0.7f * W1[e0] + 0.3f * W2[e0];
        float hi = 1.75f * W0[e1] + 0.7f * W1[e1] + 0.3f * W2[e1];
        Bt[idx] = pack2_bf16(lo, hi);
    }
}

// dense 4 rows from bf16 source -> Atw[k2=lane][r] (raw uint copies)
__device__ __forceinline__ void load_rows(const unsigned int* __restrict__ xb,
                                          int base, int N, int lane,
                                          unsigned int* atw) {
    uint4 w;
    unsigned int* wp = (unsigned int*)&w;
#pragma unroll
    for (int i = 0; i < 4; ++i) {
        int row = base + i;
        wp[i] = (row < N) ? xb[(size_t)row * 64 + lane] : 0u;
    }
    *reinterpret_cast<uint4*>(atw + 4 * lane) = w;   // Atw[k2=lane][0..3]
}

// CSR-mean 4 rows from bf16 source (256B/edge), interleaved, fp32 accum.
__device__ __forceinline__ void gather_rows(const unsigned int* __restrict__ xb,
                                            const int* __restrict__ rp,
                                            const int* __restrict__ col, float scale,
                                            int base, int N, int lane,
                                            unsigned int* atw) {
    int s0[4], dg[4];
    int maxd = 0;
#pragma unroll
    for (int i = 0; i < 4; ++i) {
        int row = base + i;
        int e0 = (row < N) ? rp[row] : 0;
        int e1 = (row < N) ? rp[row + 1] : 0;
        s0[i] = e0;
        dg[i] = e1 - e0;
        maxd = max(maxd, dg[i]);
    }
    float a0[4] = {0.f, 0.f, 0.f, 0.f};
    float a1[4] = {0.f, 0.f, 0.f, 0.f};
#pragma unroll 2
    for (int d = 0; d < maxd; ++d) {
#pragma unroll
        for (int i = 0; i < 4; ++i) {
            if (d < dg[i]) {
                unsigned int v = xb[(size_t)col[s0[i] + d] * 64 + lane];
                a0[i] += bf16_lo(v);
                a1[i] += bf16_hi(v);
            }
        }
    }
    uint4 w;
    unsigned int* wp = (unsigned int*)&w;
#pragma unroll
    for (int i = 0; i < 4; ++i) {
        float inv = scale / fmaxf((float)dg[i], 1.0f);
        wp[i] = pack2_bf16(a0[i] * inv, a1[i] * inv);
    }
    *reinterpret_cast<uint4*>(atw + 4 * lane) = w;
}

// per k2: 1 broadcast b128 + 2 b32 + 8 dot2
__device__ __forceinline__ void kloop_dot2(const unsigned int* atw,
                                           const unsigned int* Bt,
                                           int lane, float acc[4][2]) {
#pragma unroll 4
    for (int k2 = 0; k2 < 64; ++k2) {
        uint4 aw = *reinterpret_cast<const uint4*>(atw + k2 * 4);   // broadcast
        unsigned int b0 = Bt[k2 * 128 + lane];
        unsigned int b1 = Bt[k2 * 128 + 64 + lane];
        acc[0][0] = dot2_bf16(aw.x, b0, acc[0][0]);
        acc[0][1] = dot2_bf16(aw.x, b1, acc[0][1]);
        acc[1][0] = dot2_bf16(aw.y, b0, acc[1][0]);
        acc[1][1] = dot2_bf16(aw.y, b1, acc[1][1]);
        acc[2][0] = dot2_bf16(aw.z, b0, acc[2][0]);
        acc[2][1] = dot2_bf16(aw.z, b1, acc[2][1]);
        acc[3][0] = dot2_bf16(aw.w, b0, acc[3][0]);
        acc[3][1] = dot2_bf16(aw.w, b1, acc[3][1]);
    }
}

// --------------------------------------------------------- fused main bodies
__device__ void user_body(
        int blk, const unsigned int* __restrict__ xub,
        const unsigned int* __restrict__ xpb,
        const int* __restrict__ rp_re, const int* __restrict__ col_re,
        const int* __restrict__ rp_fb, const int* __restrict__ col_fb,
        const int* __restrict__ rp_soc, const int* __restrict__ col_soc,
        const float* __restrict__ Wl_d, const float* __restrict__ Wl_a,
        const float* __restrict__ Wl_s, const float* __restrict__ WrD,
        const float* __restrict__ WrA, const float* __restrict__ WrS,
        const float* __restrict__ bD, const float* __restrict__ bA,
        const float* __restrict__ bS, float* __restrict__ out,
        unsigned int* Bt, unsigned int (*Atw)[256]) {
    int wave = threadIdx.x >> 6, lane = threadIdx.x & 63;
    int base = (blk * 8 + wave) * 4;
    float acc[4][2] = {{0.f,0.f},{0.f,0.f},{0.f,0.f},{0.f,0.f}};
    stage_Bt(Wl_d, Bt, threadIdx.x);
    __syncthreads();
    gather_rows(xpb, rp_re, col_re, 1.75f, base, N_USER, lane, Atw[wave]);
    kloop_dot2(Atw[wave], Bt, lane, acc);
    __syncthreads();
    stage_Bt(Wl_a, Bt, threadIdx.x);
    __syncthreads();
    gather_rows(xpb, rp_fb, col_fb, 0.7f, base, N_USER, lane, Atw[wave]);
    kloop_dot2(Atw[wave], Bt, lane, acc);
    __syncthreads();
    stage_Bt(Wl_s, Bt, threadIdx.x);
    __syncthreads();
    gather_rows(xub, rp_soc, col_soc, 0.3f, base, N_USER, lane, Atw[wave]);
    kloop_dot2(Atw[wave], Bt, lane, acc);
    __syncthreads();
    stage_Bt_comb(WrD, WrA, WrS, Bt, threadIdx.x);
    __syncthreads();
    load_rows(xub, base, N_USER, lane, Atw[wave]);
    kloop_dot2(Atw[wave], Bt, lane, acc);
    float bc0 = 1.75f*bD[lane]    + 0.7f*bA[lane]    + 0.3f*bS[lane];
    float bc1 = 1.75f*bD[lane+64] + 0.7f*bA[lane+64] + 0.3f*bS[lane+64];
#pragma unroll
    for (int i = 0; i < 4; ++i) {
        int row = base + i;
        if (row < N_USER) {
            out[(size_t)row * DD + lane]      = fmaxf(acc[i][0] + bc0, 0.f);
            out[(size_t)row * DD + lane + 64] = fmaxf(acc[i][1] + bc1, 0.f);
        }
    }
}

__device__ void post_body(
        int blk, const unsigned int* __restrict__ xub,
        const int* __restrict__ rp, const int* __restrict__ col,
        const unsigned int* __restrict__ xpb,
        const float* __restrict__ Wl, const float* __restrict__ Wr,
        const float* __restrict__ bias, float* __restrict__ out,
        unsigned int* Bt, unsigned int (*Atw)[256]) {
    int wave = threadIdx.x >> 6, lane = threadIdx.x & 63;
    int base = (blk * 8 + wave) * 4;
    float acc[4][2] = {{0.f,0.f},{0.f,0.f},{0.f,0.f},{0.f,0.f}};
    stage_Bt(Wl, Bt, threadIdx.x);
    __syncthreads();
    gather_rows(xub, rp, col, 1.0f, base, N_POST, lane, Atw[wave]);
    kloop_dot2(Atw[wave], Bt, lane, acc);
    __syncthreads();
    stage_Bt(Wr, Bt, threadIdx.x);
    __syncthreads();
    load_rows(xpb, base, N_POST, lane, Atw[wave]);
    kloop_dot2(Atw[wave], Bt, lane, acc);
    float b0 = bias[lane], b1 = bias[lane + 64];
#pragma unroll
    for (int i = 0; i < 4; ++i) {
        int row = base + i;
        if (row < N_POST) {
            out[(size_t)row * DD + lane]      = fmaxf(acc[i][0] + b0, 0.f);
            out[(size_t)row * DD + lane + 64] = fmaxf(acc[i][1] + b1, 0.f);
        }
    }
}

// user blocks [0, GU), post blocks [GU, GU+GP)
__global__ __launch_bounds__(512) void main_fused_kernel(
        const unsigned int* __restrict__ xub, const unsigned int* __restrict__ xpb,
        const int* __restrict__ rp_re, const int* __restrict__ col_re,
        const int* __restrict__ rp_fb, const int* __restrict__ col_fb,
        const int* __restrict__ rp_soc, const int* __restrict__ col_soc,
        const int* __restrict__ rp_post, const int* __restrict__ col_post,
        const float* __restrict__ Wl_d, const float* __restrict__ Wl_a,
        const float* __restrict__ Wl_s, const float* __restrict__ WrD,
        const float* __restrict__ WrA, const float* __restrict__ WrS,
        const float* __restrict__ bD, const float* __restrict__ bA,
        const float* __restrict__ bS, const float* __restrict__ Wl_p,
        const float* __restrict__ Wr_p, const float* __restrict__ bl_p,
        float* __restrict__ out_user, float* __restrict__ out_post) {
    __shared__ unsigned int Bt[64 * 128];        // 32 KB
    __shared__ unsigned int Atw[8][256];         // 8 KB -> 40 KB, 4 blk/CU
    if (blockIdx.x < GU) {
        user_body(blockIdx.x, xub, xpb, rp_re, col_re, rp_fb, col_fb,
                  rp_soc, col_soc, Wl_d, Wl_a, Wl_s, WrD, WrA, WrS,
                  bD, bA, bS, out_user, Bt, Atw);
    } else {
        post_body(blockIdx.x - GU, xub, rp_post, col_post, xpb,
                  Wl_p, Wr_p, bl_p, out_post, Bt, Atw);
    }
}

// ------------------------------------------------------------------ launch --
extern "C" void kernel_launch(void* const* d_in, const int* in_sizes, int n_in,
                              void* d_out, int out_size, void* d_ws, size_t ws_size,
                              hipStream_t stream) {
    const float* x_user  = (const float*)d_in[0];
    const float* x_post  = (const float*)d_in[1];
    const int*   re_src  = (const int*)d_in[2];
    const int*   re_dst  = (const int*)d_in[3];
    const int*   fb_src  = (const int*)d_in[4];
    const int*   fb_dst  = (const int*)d_in[5];
    const int*   soc_src = (const int*)d_in[6];
    const int*   soc_dst = (const int*)d_in[7];
    const int*   eng_src = (const int*)d_in[8];
    const int*   eng_dst = (const int*)d_in[9];
    const float* Wl_d = (const float*)d_in[10];
    const float* bl_d = (const float*)d_in[11];
    const float* Wr_d = (const float*)d_in[12];
    const float* Wl_a = (const float*)d_in[13];
    const float* bl_a = (const float*)d_in[14];
    const float* Wr_a = (const float*)d_in[15];
    const float* Wl_s = (const float*)d_in[16];
    const float* bl_s = (const float*)d_in[17];
    const float* Wr_s = (const float*)d_in[18];
    const float* Wl_p = (const float*)d_in[19];
    const float* bl_p = (const float*)d_in[20];
    const float* Wr_p = (const float*)d_in[21];

    const int E_re  = in_sizes[2];
    const int E_fb  = in_sizes[4];
    const int E_soc = in_sizes[6];
    const int E_eng = in_sizes[8];

    int* ib = (int*)d_ws;
    int* rp_re    = ib;
    int* rp_fb    = rp_re   + (N_USER + 1);
    int* rp_soc   = rp_fb   + (N_USER + 1);
    int* rp_post  = rp_soc  + (N_USER + 1);
    int* wcur_re  = rp_post + (N_POST + 1);
    int* wcur_fb  = wcur_re + N_USER;
    int* wcur_soc = wcur_fb + N_USER;
    int* wcur_post= wcur_soc+ N_USER;
    int* psum     = wcur_post + N_POST;      // 4 x 64 slices
    int* col_re   = psum + 256;
    int* col_fb   = col_re  + E_re;
    int* col_soc  = col_fb  + E_fb;
    int* col_post = col_soc + E_soc;
    unsigned int* xub = (unsigned int*)(col_post + E_eng);      // 6.4M uints
    unsigned int* xpb = xub + (size_t)N_USER * 64;              // 12.8M uints

    float* out_user = (float*)d_out;
    float* out_post = out_user + (size_t)N_USER * DD;

    // one memset over rp + wcur + psum (contiguous)
    size_t zero_ints = (size_t)(N_USER + 1) * 3 + (N_POST + 1)
                     + (size_t)N_USER * 3 + N_POST + 256;
    hipMemsetAsync(rp_re, 0, zero_ints * sizeof(int), stream);

    conv_bf16<<<2048, 256, 0, stream>>>(x_user, x_post, xub, xpb);

    hist_all<<<2048, 256, 0, stream>>>(re_dst, E_re, rp_re,
                                       fb_dst, E_fb, rp_fb,
                                       soc_dst, E_soc, rp_soc,
                                       eng_dst, E_eng, rp_post);

    const int SC_BLOCKS_ALL = 3 * NBU + NBP;   // 124
    scan_partial_all<<<SC_BLOCKS_ALL, SCB, 0, stream>>>(rp_re, rp_fb, rp_soc,
                                                        rp_post, psum);
    scan_psum_all<<<4, 1024, 0, stream>>>(psum);
    scan_final_all<<<SC_BLOCKS_ALL, SCB, 0, stream>>>(rp_re, rp_fb, rp_soc,
                                                      rp_post, psum,
                                                      E_re, E_fb, E_soc, E_eng);

    fill_all<<<2048, 256, 0, stream>>>(
        re_src,  re_dst,  E_re,  rp_re,   wcur_re,   col_re,
        fb_src,  fb_dst,  E_fb,  rp_fb,   wcur_fb,   col_fb,
        soc_src, soc_dst, E_soc, rp_soc,  wcur_soc,  col_soc,
        eng_src, eng_dst, E_eng, rp_post, wcur_post, col_post);

    main_fused_kernel<<<GU + GP, 512, 0, stream>>>(
        xub, xpb, rp_re, col_re, rp_fb, col_fb, rp_soc, col_soc,
        rp_post, col_post, Wl_d, Wl_a, Wl_s, Wr_d, Wr_a, Wr_s,
        bl_d, bl_a, bl_s, Wl_p, Wr_p, bl_p, out_user, out_post);
}

// Round 27
// 1308.383 us; speedup vs baseline: 1.1117x; 1.0077x over previous
//
#include <hip/hip_runtime.h>

// WeightedRGCN on MI355X. Round 27: R26 base (1318us) + conv_bf16 merged
// into hist_all as one `prep_all` dispatch (BW-bound convert + atomic-bound
// histogram use orthogonal resources -> runtime ~max not sum; one less
// launch). No numeric change: predict absmax 0.0625.
//
// ws (ints): rp x4, wcur x4, psum(256), col x4 (5.6M), xub (6.4M),
// xpb (12.8M)  => ~25.9M ints = 103.6MB.

#define N_USER 100000
#define N_POST 200000
#define DD 128
#define GU 3125            // 100000/32 rows per block
#define GP 6250            // 200000/32

__device__ __forceinline__ unsigned int pack2_bf16(float lo, float hi) {
    unsigned int ulo, uhi;
    __builtin_memcpy(&ulo, &lo, 4);
    __builtin_memcpy(&uhi, &hi, 4);
    unsigned int rlo = (ulo + 0x7fffu + ((ulo >> 16) & 1u)) >> 16;   // RNE
    unsigned int rhi = (uhi + 0x7fffu + ((uhi >> 16) & 1u)) >> 16;
    return (rlo & 0xffffu) | (rhi << 16);
}
__device__ __forceinline__ float bf16_lo(unsigned int u) {
    unsigned int t = u << 16; float f; __builtin_memcpy(&f, &t, 4); return f;
}
__device__ __forceinline__ float bf16_hi(unsigned int u) {
    unsigned int t = u & 0xffff0000u; float f; __builtin_memcpy(&f, &t, 4); return f;
}

// D = a.lo*b.lo + a.hi*b.hi + c   (packed bf16 dot-2, fp32 accumulate)
__device__ __forceinline__ float dot2_bf16(unsigned int a, unsigned int b, float c) {
    float r;
    asm("v_dot2_f32_bf16 %0, %1, %2, %3" : "=v"(r) : "v"(a), "v"(b), "v"(c));
    return r;
}

// ------------------------------------------- prep: bf16 convert + histogram -
// items [0, NU+NP): feature converts; [NU+NP, +Etot): histogram atomics.
__global__ __launch_bounds__(256) void prep_all(
        const float* __restrict__ xu, const float* __restrict__ xp,
        unsigned int* __restrict__ xub, unsigned int* __restrict__ xpb,
        const int* __restrict__ d0, int e0, int* __restrict__ c0,
        const int* __restrict__ d1, int e1, int* __restrict__ c1,
        const int* __restrict__ d2, int e2, int* __restrict__ c2,
        const int* __restrict__ d3, int e3, int* __restrict__ c3) {
    const int NU = N_USER * 64, NP = N_POST * 64;   // uint counts
    const int NC = NU + NP;
    int b1 = e0, b2 = e0 + e1, b3 = e0 + e1 + e2;
    int tot = NC + b3 + e3;
    int i = blockIdx.x * 256 + threadIdx.x;
    int stride = gridDim.x * 256;
    for (int t = i; t < tot; t += stride) {
        if (t < NU) {
            float2 v = ((const float2*)xu)[t];
            xub[t] = pack2_bf16(v.x, v.y);
        } else if (t < NC) {
            float2 v = ((const float2*)xp)[t - NU];
            xpb[t - NU] = pack2_bf16(v.x, v.y);
        } else {
            int h = t - NC;
            if (h < b1)      atomicAdd(&c0[d0[h]], 1);
            else if (h < b2) atomicAdd(&c1[d1[h - b1]], 1);
            else if (h < b3) atomicAdd(&c2[d2[h - b2]], 1);
            else             atomicAdd(&c3[d3[h - b3]], 1);
        }
    }
}

// -------------------------------------------------- CSR build (R22 verbatim)
__global__ __launch_bounds__(256) void fill_all(
        const int* __restrict__ s0, const int* __restrict__ d0, int e0,
        const int* __restrict__ r0, int* __restrict__ w0, int* __restrict__ o0,
        const int* __restrict__ s1, const int* __restrict__ d1, int e1,
        const int* __restrict__ r1, int* __restrict__ w1, int* __restrict__ o1,
        const int* __restrict__ s2, const int* __restrict__ d2, int e2,
        const int* __restrict__ r2, int* __restrict__ w2, int* __restrict__ o2,
        const int* __restrict__ s3, const int* __restrict__ d3, int e3,
        const int* __restrict__ r3, int* __restrict__ w3, int* __restrict__ o3) {
    int i = blockIdx.x * 256 + threadIdx.x;
    int stride = gridDim.x * 256;
    int b1 = e0, b2 = e0 + e1, b3 = e0 + e1 + e2, tot = b3 + e3;
    for (int t = i; t < tot; t += stride) {
        if (t < b1)      { int e = t;      int d = d0[e]; o0[r0[d] + atomicAdd(&w0[d], 1)] = s0[e]; }
        else if (t < b2) { int e = t - b1; int d = d1[e]; o1[r1[d] + atomicAdd(&w1[d], 1)] = s1[e]; }
        else if (t < b3) { int e = t - b2; int d = d2[e]; o2[r2[d] + atomicAdd(&w2[d], 1)] = s2[e]; }
        else             { int e = t - b3; int d = d3[e]; o3[r3[d] + atomicAdd(&w3[d], 1)] = s3[e]; }
    }
}

#define SCB 256
#define SCE 16
#define SCCH (SCB * SCE)   // 4096
#define NBU 25
#define NBP 49

__device__ __forceinline__ void seg_map(int b, int* rp0, int* rp1, int* rp2,
                                        int* rp3, int* psum,
                                        int** a, int* N, int** ps, int* lb) {
    if (b < NBU)            { *a = rp0; *N = N_USER; *ps = psum;       *lb = b; }
    else if (b < 2 * NBU)   { *a = rp1; *N = N_USER; *ps = psum + 64;  *lb = b - NBU; }
    else if (b < 3 * NBU)   { *a = rp2; *N = N_USER; *ps = psum + 128; *lb = b - 2 * NBU; }
    else                    { *a = rp3; *N = N_POST; *ps = psum + 192; *lb = b - 3 * NBU; }
}

__global__ __launch_bounds__(SCB) void scan_partial_all(
        int* rp0, int* rp1, int* rp2, int* rp3, int* psum) {
    int* a; int N; int* ps; int lb;
    seg_map(blockIdx.x, rp0, rp1, rp2, rp3, psum, &a, &N, &ps, &lb);
    __shared__ int red[SCB];
    int tid = threadIdx.x;
    int i0 = lb * SCCH + tid * SCE;
    int s = 0;
#pragma unroll
    for (int j = 0; j < SCE; ++j) { int i = i0 + j; if (i < N) s += a[i]; }
    red[tid] = s;
    __syncthreads();
    for (int off = SCB / 2; off > 0; off >>= 1) {
        if (tid < off) red[tid] += red[tid + off];
        __syncthreads();
    }
    if (tid == 0) ps[lb] = red[0];
}

__global__ __launch_bounds__(1024) void scan_psum_all(int* __restrict__ psum) {
    __shared__ int t[1024];
    int tid = threadIdx.x;
    int nb = (blockIdx.x == 3) ? NBP : NBU;
    int* ps = psum + blockIdx.x * 64;
    int v = (tid < nb) ? ps[tid] : 0;
    t[tid] = v;
    __syncthreads();
    for (int off = 1; off < 1024; off <<= 1) {
        int u = (tid >= off) ? t[tid - off] : 0;
        __syncthreads();
        t[tid] += u;
        __syncthreads();
    }
    if (tid < nb) ps[tid] = t[tid] - v;   // exclusive
}

__global__ __launch_bounds__(SCB) void scan_final_all(
        int* rp0, int* rp1, int* rp2, int* rp3, int* psum,
        int E0, int E1, int E2, int E3) {
    int* a; int N; int* ps; int lb;
    seg_map(blockIdx.x, rp0, rp1, rp2, rp3, psum, &a, &N, &ps, &lb);
    int E = (blockIdx.x < NBU) ? E0 : (blockIdx.x < 2*NBU) ? E1
          : (blockIdx.x < 3*NBU) ? E2 : E3;
    __shared__ int red[SCB];
    int tid = threadIdx.x;
    int i0 = lb * SCCH + tid * SCE;
    int v[SCE];
    int s = 0;
#pragma unroll
    for (int j = 0; j < SCE; ++j) { int i = i0 + j; v[j] = (i < N) ? a[i] : 0; s += v[j]; }
    red[tid] = s;
    __syncthreads();
    for (int off = 1; off < SCB; off <<= 1) {   // inclusive Hillis-Steele
        int u = (tid >= off) ? red[tid - off] : 0;
        __syncthreads();
        red[tid] += u;
        __syncthreads();
    }
    int run = ps[lb] + red[tid] - s;
#pragma unroll
    for (int j = 0; j < SCE; ++j) { int i = i0 + j; if (i < N) a[i] = run; run += v[j]; }
    if (lb == 0 && tid == 0) a[N] = E;
}

// ------------------------------------------------------------ GEMM pieces ---
// Bt[k2][c] = (B[2k2][c], B[2k2+1][c])  -- k-pair packed, 64x128 words = 32KB
__device__ __forceinline__ void stage_Bt(const float* __restrict__ B,
                                         unsigned int* Bt, int tid) {
    for (int idx = tid; idx < 64 * 128; idx += 512) {
        int k2 = idx >> 7, c = idx & 127;
        Bt[idx] = pack2_bf16(B[(2 * k2) * 128 + c], B[(2 * k2 + 1) * 128 + c]);
    }
}
__device__ __forceinline__ void stage_Bt_comb(const float* __restrict__ W0,
                                              const float* __restrict__ W1,
                                              const float* __restrict__ W2,
                                              unsigned int* Bt, int tid) {
    for (int idx = tid; idx < 64 * 128; idx += 512) {
        int k2 = idx >> 7, c = idx & 127;
        int e0 = (2 * k2) * 128 + c, e1 = (2 * k2 + 1) * 128 + c;
        float lo = 1.75f * W0[e0] + 0.7f * W1[e0] + 0.3f * W2[e0];
        float hi = 1.75f * W0[e1] + 0.7f * W1[e1] + 0.3f * W2[e1];
        Bt[idx] = pack2_bf16(lo, hi);
    }
}

// dense 4 rows from bf16 source -> Atw[k2=lane][r] (raw uint copies)
__device__ __forceinline__ void load_rows(const unsigned int* __restrict__ xb,
                                          int base, int N, int lane,
                                          unsigned int* atw) {
    uint4 w;
    unsigned int* wp = (unsigned int*)&w;
#pragma unroll
    for (int i = 0; i < 4; ++i) {
        int row = base + i;
        wp[i] = (row < N) ? xb[(size_t)row * 64 + lane] : 0u;
    }
    *reinterpret_cast<uint4*>(atw + 4 * lane) = w;   // Atw[k2=lane][0..3]
}

// CSR-mean 4 rows from bf16 source (256B/edge), interleaved, fp32 accum.
__device__ __forceinline__ void gather_rows(const unsigned int* __restrict__ xb,
                                            const int* __restrict__ rp,
                                            const int* __restrict__ col, float scale,
                                            int base, int N, int lane,
                                            unsigned int* atw) {
    int s0[4], dg[4];
    int maxd = 0;
#pragma unroll
    for (int i = 0; i < 4; ++i) {
        int row = base + i;
        int e0 = (row < N) ? rp[row] : 0;
        int e1 = (row < N) ? rp[row + 1] : 0;
        s0[i] = e0;
        dg[i] = e1 - e0;
        maxd = max(maxd, dg[i]);
    }
    float a0[4] = {0.f, 0.f, 0.f, 0.f};
    float a1[4] = {0.f, 0.f, 0.f, 0.f};
#pragma unroll 2
    for (int d = 0; d < maxd; ++d) {
#pragma unroll
        for (int i = 0; i < 4; ++i) {
            if (d < dg[i]) {
                unsigned int v = xb[(size_t)col[s0[i] + d] * 64 + lane];
                a0[i] += bf16_lo(v);
                a1[i] += bf16_hi(v);
            }
        }
    }
    uint4 w;
    unsigned int* wp = (unsigned int*)&w;
#pragma unroll
    for (int i = 0; i < 4; ++i) {
        float inv = scale / fmaxf((float)dg[i], 1.0f);
        wp[i] = pack2_bf16(a0[i] * inv, a1[i] * inv);
    }
    *reinterpret_cast<uint4*>(atw + 4 * lane) = w;
}

// per k2: 1 broadcast b128 + 2 b32 + 8 dot2
__device__ __forceinline__ void kloop_dot2(const unsigned int* atw,
                                           const unsigned int* Bt,
                                           int lane, float acc[4][2]) {
#pragma unroll 4
    for (int k2 = 0; k2 < 64; ++k2) {
        uint4 aw = *reinterpret_cast<const uint4*>(atw + k2 * 4);   // broadcast
        unsigned int b0 = Bt[k2 * 128 + lane];
        unsigned int b1 = Bt[k2 * 128 + 64 + lane];
        acc[0][0] = dot2_bf16(aw.x, b0, acc[0][0]);
        acc[0][1] = dot2_bf16(aw.x, b1, acc[0][1]);
        acc[1][0] = dot2_bf16(aw.y, b0, acc[1][0]);
        acc[1][1] = dot2_bf16(aw.y, b1, acc[1][1]);
        acc[2][0] = dot2_bf16(aw.z, b0, acc[2][0]);
        acc[2][1] = dot2_bf16(aw.z, b1, acc[2][1]);
        acc[3][0] = dot2_bf16(aw.w, b0, acc[3][0]);
        acc[3][1] = dot2_bf16(aw.w, b1, acc[3][1]);
    }
}

// --------------------------------------------------------- fused main bodies
__device__ void user_body(
        int blk, const unsigned int* __restrict__ xub,
        const unsigned int* __restrict__ xpb,
        const int* __restrict__ rp_re, const int* __restrict__ col_re,
        const int* __restrict__ rp_fb, const int* __restrict__ col_fb,
        const int* __restrict__ rp_soc, const int* __restrict__ col_soc,
        const float* __restrict__ Wl_d, const float* __restrict__ Wl_a,
        const float* __restrict__ Wl_s, const float* __restrict__ WrD,
        const float* __restrict__ WrA, const float* __restrict__ WrS,
        const float* __restrict__ bD, const float* __restrict__ bA,
        const float* __restrict__ bS, float* __restrict__ out,
        unsigned int* Bt, unsigned int (*Atw)[256]) {
    int wave = threadIdx.x >> 6, lane = threadIdx.x & 63;
    int base = (blk * 8 + wave) * 4;
    float acc[4][2] = {{0.f,0.f},{0.f,0.f},{0.f,0.f},{0.f,0.f}};
    stage_Bt(Wl_d, Bt, threadIdx.x);
    __syncthreads();
    gather_rows(xpb, rp_re, col_re, 1.75f, base, N_USER, lane, Atw[wave]);
    kloop_dot2(Atw[wave], Bt, lane, acc);
    __syncthreads();
    stage_Bt(Wl_a, Bt, threadIdx.x);
    __syncthreads();
    gather_rows(xpb, rp_fb, col_fb, 0.7f, base, N_USER, lane, Atw[wave]);
    kloop_dot2(Atw[wave], Bt, lane, acc);
    __syncthreads();
    stage_Bt(Wl_s, Bt, threadIdx.x);
    __syncthreads();
    gather_rows(xub, rp_soc, col_soc, 0.3f, base, N_USER, lane, Atw[wave]);
    kloop_dot2(Atw[wave], Bt, lane, acc);
    __syncthreads();
    stage_Bt_comb(WrD, WrA, WrS, Bt, threadIdx.x);
    __syncthreads();
    load_rows(xub, base, N_USER, lane, Atw[wave]);
    kloop_dot2(Atw[wave], Bt, lane, acc);
    float bc0 = 1.75f*bD[lane]    + 0.7f*bA[lane]    + 0.3f*bS[lane];
    float bc1 = 1.75f*bD[lane+64] + 0.7f*bA[lane+64] + 0.3f*bS[lane+64];
#pragma unroll
    for (int i = 0; i < 4; ++i) {
        int row = base + i;
        if (row < N_USER) {
            out[(size_t)row * DD + lane]      = fmaxf(acc[i][0] + bc0, 0.f);
            out[(size_t)row * DD + lane + 64] = fmaxf(acc[i][1] + bc1, 0.f);
        }
    }
}

__device__ void post_body(
        int blk, const unsigned int* __restrict__ xub,
        const int* __restrict__ rp, const int* __restrict__ col,
        const unsigned int* __restrict__ xpb,
        const float* __restrict__ Wl, const float* __restrict__ Wr,
        const float* __restrict__ bias, float* __restrict__ out,
        unsigned int* Bt, unsigned int (*Atw)[256]) {
    int wave = threadIdx.x >> 6, lane = threadIdx.x & 63;
    int base = (blk * 8 + wave) * 4;
    float acc[4][2] = {{0.f,0.f},{0.f,0.f},{0.f,0.f},{0.f,0.f}};
    stage_Bt(Wl, Bt, threadIdx.x);
    __syncthreads();
    gather_rows(xub, rp, col, 1.0f, base, N_POST, lane, Atw[wave]);
    kloop_dot2(Atw[wave], Bt, lane, acc);
    __syncthreads();
    stage_Bt(Wr, Bt, threadIdx.x);
    __syncthreads();
    load_rows(xpb, base, N_POST, lane, Atw[wave]);
    kloop_dot2(Atw[wave], Bt, lane, acc);
    float b0 = bias[lane], b1 = bias[lane + 64];
#pragma unroll
    for (int i = 0; i < 4; ++i) {
        int row = base + i;
        if (row < N_POST) {
            out[(size_t)row * DD + lane]      = fmaxf(acc[i][0] + b0, 0.f);
            out[(size_t)row * DD + lane + 64] = fmaxf(acc[i][1] + b1, 0.f);
        }
    }
}

// user blocks [0, GU), post blocks [GU, GU+GP)
__global__ __launch_bounds__(512) void main_fused_kernel(
        const unsigned int* __restrict__ xub, const unsigned int* __restrict__ xpb,
        const int* __restrict__ rp_re, const int* __restrict__ col_re,
        const int* __restrict__ rp_fb, const int* __restrict__ col_fb,
        const int* __restrict__ rp_soc, const int* __restrict__ col_soc,
        const int* __restrict__ rp_post, const int* __restrict__ col_post,
        const float* __restrict__ Wl_d, const float* __restrict__ Wl_a,
        const float* __restrict__ Wl_s, const float* __restrict__ WrD,
        const float* __restrict__ WrA, const float* __restrict__ WrS,
        const float* __restrict__ bD, const float* __restrict__ bA,
        const float* __restrict__ bS, const float* __restrict__ Wl_p,
        const float* __restrict__ Wr_p, const float* __restrict__ bl_p,
        float* __restrict__ out_user, float* __restrict__ out_post) {
    __shared__ unsigned int Bt[64 * 128];        // 32 KB
    __shared__ unsigned int Atw[8][256];         // 8 KB -> 40 KB, 4 blk/CU
    if (blockIdx.x < GU) {
        user_body(blockIdx.x, xub, xpb, rp_re, col_re, rp_fb, col_fb,
                  rp_soc, col_soc, Wl_d, Wl_a, Wl_s, WrD, WrA, WrS,
                  bD, bA, bS, out_user, Bt, Atw);
    } else {
        post_body(blockIdx.x - GU, xub, rp_post, col_post, xpb,
                  Wl_p, Wr_p, bl_p, out_post, Bt, Atw);
    }
}

// ------------------------------------------------------------------ launch --
extern "C" void kernel_launch(void* const* d_in, const int* in_sizes, int n_in,
                              void* d_out, int out_size, void* d_ws, size_t ws_size,
                              hipStream_t stream) {
    const float* x_user  = (const float*)d_in[0];
    const float* x_post  = (const float*)d_in[1];
    const int*   re_src  = (const int*)d_in[2];
    const int*   re_dst  = (const int*)d_in[3];
    const int*   fb_src  = (const int*)d_in[4];
    const int*   fb_dst  = (const int*)d_in[5];
    const int*   soc_src = (const int*)d_in[6];
    const int*   soc_dst = (const int*)d_in[7];
    const int*   eng_src = (const int*)d_in[8];
    const int*   eng_dst = (const int*)d_in[9];
    const float* Wl_d = (const float*)d_in[10];
    const float* bl_d = (const float*)d_in[11];
    const float* Wr_d = (const float*)d_in[12];
    const float* Wl_a = (const float*)d_in[13];
    const float* bl_a = (const float*)d_in[14];
    const float* Wr_a = (const float*)d_in[15];
    const float* Wl_s = (const float*)d_in[16];
    const float* bl_s = (const float*)d_in[17];
    const float* Wr_s = (const float*)d_in[18];
    const float* Wl_p = (const float*)d_in[19];
    const float* bl_p = (const float*)d_in[20];
    const float* Wr_p = (const float*)d_in[21];

    const int E_re  = in_sizes[2];
    const int E_fb  = in_sizes[4];
    const int E_soc = in_sizes[6];
    const int E_eng = in_sizes[8];

    int* ib = (int*)d_ws;
    int* rp_re    = ib;
    int* rp_fb    = rp_re   + (N_USER + 1);
    int* rp_soc   = rp_fb   + (N_USER + 1);
    int* rp_post  = rp_soc  + (N_USER + 1);
    int* wcur_re  = rp_post + (N_POST + 1);
    int* wcur_fb  = wcur_re + N_USER;
    int* wcur_soc = wcur_fb + N_USER;
    int* wcur_post= wcur_soc+ N_USER;
    int* psum     = wcur_post + N_POST;      // 4 x 64 slices
    int* col_re   = psum + 256;
    int* col_fb   = col_re  + E_re;
    int* col_soc  = col_fb  + E_fb;
    int* col_post = col_soc + E_soc;
    unsigned int* xub = (unsigned int*)(col_post + E_eng);      // 6.4M uints
    unsigned int* xpb = xub + (size_t)N_USER * 64;              // 12.8M uints

    float* out_user = (float*)d_out;
    float* out_post = out_user + (size_t)N_USER * DD;

    // one memset over rp + wcur + psum (contiguous)
    size_t zero_ints = (size_t)(N_USER + 1) * 3 + (N_POST + 1)
                     + (size_t)N_USER * 3 + N_POST + 256;
    hipMemsetAsync(rp_re, 0, zero_ints * sizeof(int), stream);

    // merged: bf16 feature conversion + 4-relation histogram
    prep_all<<<2048, 256, 0, stream>>>(x_user, x_post, xub, xpb,
                                       re_dst, E_re, rp_re,
                                       fb_dst, E_fb, rp_fb,
                                       soc_dst, E_soc, rp_soc,
                                       eng_dst, E_eng, rp_post);

    const int SC_BLOCKS_ALL = 3 * NBU + NBP;   // 124
    scan_partial_all<<<SC_BLOCKS_ALL, SCB, 0, stream>>>(rp_re, rp_fb, rp_soc,
                                                        rp_post, psum);
    scan_psum_all<<<4, 1024, 0, stream>>>(psum);
    scan_final_all<<<SC_BLOCKS_ALL, SCB, 0, stream>>>(rp_re, rp_fb, rp_soc,
                                                      rp_post, psum,
                                                      E_re, E_fb, E_soc, E_eng);

    fill_all<<<2048, 256, 0, stream>>>(
        re_src,  re_dst,  E_re,  rp_re,   wcur_re,   col_re,
        fb_src,  fb_dst,  E_fb,  rp_fb,   wcur_fb,   col_fb,
        soc_src, soc_dst, E_soc, rp_soc,  wcur_soc,  col_soc,
        eng_src, eng_dst, E_eng, rp_post, wcur_post, col_post);

    main_fused_kernel<<<GU + GP, 512, 0, stream>>>(
        xub, xpb, rp_re, col_re, rp_fb, col_fb, rp_soc, col_soc,
        rp_post, col_post, Wl_d, Wl_a, Wl_s, Wr_d, Wr_a, Wr_s,
        bl_d, bl_a, bl_s, Wl_p, Wr_p, bl_p, out_user, out_post);
}

// Round 28
// 1062.286 us; speedup vs baseline: 1.3693x; 1.2317x over previous
//
#include <hip/hip_runtime.h>

// WeightedRGCN on MI355X. Round 28: R27 base (1308us) with gather_rows
// switched from 4-row masked interleave (maxd*4 ~ 96 issued iters/wave,
// ~33% masked waste) to SEQUENTIAL per-row loops (sum dg ~ 64 iters),
// unroll 4 within each row. R24 proved load-depth neutral => issue-bound
// => fewer issued iterations is a direct win. Everything else identical.
// No numeric change: predict absmax 0.0625.

#define N_USER 100000
#define N_POST 200000
#define DD 128
#define GU 3125            // 100000/32 rows per block
#define GP 6250            // 200000/32

__device__ __forceinline__ unsigned int pack2_bf16(float lo, float hi) {
    unsigned int ulo, uhi;
    __builtin_memcpy(&ulo, &lo, 4);
    __builtin_memcpy(&uhi, &hi, 4);
    unsigned int rlo = (ulo + 0x7fffu + ((ulo >> 16) & 1u)) >> 16;   // RNE
    unsigned int rhi = (uhi + 0x7fffu + ((uhi >> 16) & 1u)) >> 16;
    return (rlo & 0xffffu) | (rhi << 16);
}
__device__ __forceinline__ float bf16_lo(unsigned int u) {
    unsigned int t = u << 16; float f; __builtin_memcpy(&f, &t, 4); return f;
}
__device__ __forceinline__ float bf16_hi(unsigned int u) {
    unsigned int t = u & 0xffff0000u; float f; __builtin_memcpy(&f, &t, 4); return f;
}

// D = a.lo*b.lo + a.hi*b.hi + c   (packed bf16 dot-2, fp32 accumulate)
__device__ __forceinline__ float dot2_bf16(unsigned int a, unsigned int b, float c) {
    float r;
    asm("v_dot2_f32_bf16 %0, %1, %2, %3" : "=v"(r) : "v"(a), "v"(b), "v"(c));
    return r;
}

// ------------------------------------------- prep: bf16 convert + histogram -
__global__ __launch_bounds__(256) void prep_all(
        const float* __restrict__ xu, const float* __restrict__ xp,
        unsigned int* __restrict__ xub, unsigned int* __restrict__ xpb,
        const int* __restrict__ d0, int e0, int* __restrict__ c0,
        const int* __restrict__ d1, int e1, int* __restrict__ c1,
        const int* __restrict__ d2, int e2, int* __restrict__ c2,
        const int* __restrict__ d3, int e3, int* __restrict__ c3) {
    const int NU = N_USER * 64, NP = N_POST * 64;   // uint counts
    const int NC = NU + NP;
    int b1 = e0, b2 = e0 + e1, b3 = e0 + e1 + e2;
    int tot = NC + b3 + e3;
    int i = blockIdx.x * 256 + threadIdx.x;
    int stride = gridDim.x * 256;
    for (int t = i; t < tot; t += stride) {
        if (t < NU) {
            float2 v = ((const float2*)xu)[t];
            xub[t] = pack2_bf16(v.x, v.y);
        } else if (t < NC) {
            float2 v = ((const float2*)xp)[t - NU];
            xpb[t - NU] = pack2_bf16(v.x, v.y);
        } else {
            int h = t - NC;
            if (h < b1)      atomicAdd(&c0[d0[h]], 1);
            else if (h < b2) atomicAdd(&c1[d1[h - b1]], 1);
            else if (h < b3) atomicAdd(&c2[d2[h - b2]], 1);
            else             atomicAdd(&c3[d3[h - b3]], 1);
        }
    }
}

// -------------------------------------------------- CSR build (R22 verbatim)
__global__ __launch_bounds__(256) void fill_all(
        const int* __restrict__ s0, const int* __restrict__ d0, int e0,
        const int* __restrict__ r0, int* __restrict__ w0, int* __restrict__ o0,
        const int* __restrict__ s1, const int* __restrict__ d1, int e1,
        const int* __restrict__ r1, int* __restrict__ w1, int* __restrict__ o1,
        const int* __restrict__ s2, const int* __restrict__ d2, int e2,
        const int* __restrict__ r2, int* __restrict__ w2, int* __restrict__ o2,
        const int* __restrict__ s3, const int* __restrict__ d3, int e3,
        const int* __restrict__ r3, int* __restrict__ w3, int* __restrict__ o3) {
    int i = blockIdx.x * 256 + threadIdx.x;
    int stride = gridDim.x * 256;
    int b1 = e0, b2 = e0 + e1, b3 = e0 + e1 + e2, tot = b3 + e3;
    for (int t = i; t < tot; t += stride) {
        if (t < b1)      { int e = t;      int d = d0[e]; o0[r0[d] + atomicAdd(&w0[d], 1)] = s0[e]; }
        else if (t < b2) { int e = t - b1; int d = d1[e]; o1[r1[d] + atomicAdd(&w1[d], 1)] = s1[e]; }
        else if (t < b3) { int e = t - b2; int d = d2[e]; o2[r2[d] + atomicAdd(&w2[d], 1)] = s2[e]; }
        else             { int e = t - b3; int d = d3[e]; o3[r3[d] + atomicAdd(&w3[d], 1)] = s3[e]; }
    }
}

#define SCB 256
#define SCE 16
#define SCCH (SCB * SCE)   // 4096
#define NBU 25
#define NBP 49

__device__ __forceinline__ void seg_map(int b, int* rp0, int* rp1, int* rp2,
                                        int* rp3, int* psum,
                                        int** a, int* N, int** ps, int* lb) {
    if (b < NBU)            { *a = rp0; *N = N_USER; *ps = psum;       *lb = b; }
    else if (b < 2 * NBU)   { *a = rp1; *N = N_USER; *ps = psum + 64;  *lb = b - NBU; }
    else if (b < 3 * NBU)   { *a = rp2; *N = N_USER; *ps = psum + 128; *lb = b - 2 * NBU; }
    else                    { *a = rp3; *N = N_POST; *ps = psum + 192; *lb = b - 3 * NBU; }
}

__global__ __launch_bounds__(SCB) void scan_partial_all(
        int* rp0, int* rp1, int* rp2, int* rp3, int* psum) {
    int* a; int N; int* ps; int lb;
    seg_map(blockIdx.x, rp0, rp1, rp2, rp3, psum, &a, &N, &ps, &lb);
    __shared__ int red[SCB];
    int tid = threadIdx.x;
    int i0 = lb * SCCH + tid * SCE;
    int s = 0;
#pragma unroll
    for (int j = 0; j < SCE; ++j) { int i = i0 + j; if (i < N) s += a[i]; }
    red[tid] = s;
    __syncthreads();
    for (int off = SCB / 2; off > 0; off >>= 1) {
        if (tid < off) red[tid] += red[tid + off];
        __syncthreads();
    }
    if (tid == 0) ps[lb] = red[0];
}

__global__ __launch_bounds__(1024) void scan_psum_all(int* __restrict__ psum) {
    __shared__ int t[1024];
    int tid = threadIdx.x;
    int nb = (blockIdx.x == 3) ? NBP : NBU;
    int* ps = psum + blockIdx.x * 64;
    int v = (tid < nb) ? ps[tid] : 0;
    t[tid] = v;
    __syncthreads();
    for (int off = 1; off < 1024; off <<= 1) {
        int u = (tid >= off) ? t[tid - off] : 0;
        __syncthreads();
        t[tid] += u;
        __syncthreads();
    }
    if (tid < nb) ps[tid] = t[tid] - v;   // exclusive
}

__global__ __launch_bounds__(SCB) void scan_final_all(
        int* rp0, int* rp1, int* rp2, int* rp3, int* psum,
        int E0, int E1, int E2, int E3) {
    int* a; int N; int* ps; int lb;
    seg_map(blockIdx.x, rp0, rp1, rp2, rp3, psum, &a, &N, &ps, &lb);
    int E = (blockIdx.x < NBU) ? E0 : (blockIdx.x < 2*NBU) ? E1
          : (blockIdx.x < 3*NBU) ? E2 : E3;
    __shared__ int red[SCB];
    int tid = threadIdx.x;
    int i0 = lb * SCCH + tid * SCE;
    int v[SCE];
    int s = 0;
#pragma unroll
    for (int j = 0; j < SCE; ++j) { int i = i0 + j; v[j] = (i < N) ? a[i] : 0; s += v[j]; }
    red[tid] = s;
    __syncthreads();
    for (int off = 1; off < SCB; off <<= 1) {   // inclusive Hillis-Steele
        int u = (tid >= off) ? red[tid - off] : 0;
        __syncthreads();
        red[tid] += u;
        __syncthreads();
    }
    int run = ps[lb] + red[tid] - s;
#pragma unroll
    for (int j = 0; j < SCE; ++j) { int i = i0 + j; if (i < N) a[i] = run; run += v[j]; }
    if (lb == 0 && tid == 0) a[N] = E;
}

// ------------------------------------------------------------ GEMM pieces ---
// Bt[k2][c] = (B[2k2][c], B[2k2+1][c])  -- k-pair packed, 64x128 words = 32KB
__device__ __forceinline__ void stage_Bt(const float* __restrict__ B,
                                         unsigned int* Bt, int tid) {
    for (int idx = tid; idx < 64 * 128; idx += 512) {
        int k2 = idx >> 7, c = idx & 127;
        Bt[idx] = pack2_bf16(B[(2 * k2) * 128 + c], B[(2 * k2 + 1) * 128 + c]);
    }
}
__device__ __forceinline__ void stage_Bt_comb(const float* __restrict__ W0,
                                              const float* __restrict__ W1,
                                              const float* __restrict__ W2,
                                              unsigned int* Bt, int tid) {
    for (int idx = tid; idx < 64 * 128; idx += 512) {
        int k2 = idx >> 7, c = idx & 127;
        int e0 = (2 * k2) * 128 + c, e1 = (2 * k2 + 1) * 128 + c;
        float lo = 1.75f * W0[e0] + 0.7f * W1[e0] + 0.3f * W2[e0];
        float hi = 1.75f * W0[e1] + 0.7f * W1[e1] + 0.3f * W2[e1];
        Bt[idx] = pack2_bf16(lo, hi);
    }
}

// dense 4 rows from bf16 source -> Atw[k2=lane][r] (raw uint copies)
__device__ __forceinline__ void load_rows(const unsigned int* __restrict__ xb,
                                          int base, int N, int lane,
                                          unsigned int* atw) {
    uint4 w;
    unsigned int* wp = (unsigned int*)&w;
#pragma unroll
    for (int i = 0; i < 4; ++i) {
        int row = base + i;
        wp[i] = (row < N) ? xb[(size_t)row * 64 + lane] : 0u;
    }
    *reinterpret_cast<uint4*>(atw + 4 * lane) = w;   // Atw[k2=lane][0..3]
}

// CSR-mean 4 rows: SEQUENTIAL per-row loops (sum dg iters, no masked waste),
// unroll 4 within each row (independent loads). fp32 accumulate.
__device__ __forceinline__ void gather_rows(const unsigned int* __restrict__ xb,
                                            const int* __restrict__ rp,
                                            const int* __restrict__ col, float scale,
                                            int base, int N, int lane,
                                            unsigned int* atw) {
    uint4 w;
    unsigned int* wp = (unsigned int*)&w;
#pragma unroll
    for (int i = 0; i < 4; ++i) {
        int row = base + i;
        int e0 = (row < N) ? rp[row] : 0;
        int e1 = (row < N) ? rp[row + 1] : 0;
        float a0 = 0.f, a1 = 0.f;
#pragma unroll 4
        for (int e = e0; e < e1; ++e) {
            unsigned int v = xb[(size_t)col[e] * 64 + lane];
            a0 += bf16_lo(v);
            a1 += bf16_hi(v);
        }
        float inv = scale / fmaxf((float)(e1 - e0), 1.0f);
        wp[i] = pack2_bf16(a0 * inv, a1 * inv);
    }
    *reinterpret_cast<uint4*>(atw + 4 * lane) = w;
}

// per k2: 1 broadcast b128 + 2 b32 + 8 dot2
__device__ __forceinline__ void kloop_dot2(const unsigned int* atw,
                                           const unsigned int* Bt,
                                           int lane, float acc[4][2]) {
#pragma unroll 4
    for (int k2 = 0; k2 < 64; ++k2) {
        uint4 aw = *reinterpret_cast<const uint4*>(atw + k2 * 4);   // broadcast
        unsigned int b0 = Bt[k2 * 128 + lane];
        unsigned int b1 = Bt[k2 * 128 + 64 + lane];
        acc[0][0] = dot2_bf16(aw.x, b0, acc[0][0]);
        acc[0][1] = dot2_bf16(aw.x, b1, acc[0][1]);
        acc[1][0] = dot2_bf16(aw.y, b0, acc[1][0]);
        acc[1][1] = dot2_bf16(aw.y, b1, acc[1][1]);
        acc[2][0] = dot2_bf16(aw.z, b0, acc[2][0]);
        acc[2][1] = dot2_bf16(aw.z, b1, acc[2][1]);
        acc[3][0] = dot2_bf16(aw.w, b0, acc[3][0]);
        acc[3][1] = dot2_bf16(aw.w, b1, acc[3][1]);
    }
}

// --------------------------------------------------------- fused main bodies
__device__ void user_body(
        int blk, const unsigned int* __restrict__ xub,
        const unsigned int* __restrict__ xpb,
        const int* __restrict__ rp_re, const int* __restrict__ col_re,
        const int* __restrict__ rp_fb, const int* __restrict__ col_fb,
        const int* __restrict__ rp_soc, const int* __restrict__ col_soc,
        const float* __restrict__ Wl_d, const float* __restrict__ Wl_a,
        const float* __restrict__ Wl_s, const float* __restrict__ WrD,
        const float* __restrict__ WrA, const float* __restrict__ WrS,
        const float* __restrict__ bD, const float* __restrict__ bA,
        const float* __restrict__ bS, float* __restrict__ out,
        unsigned int* Bt, unsigned int (*Atw)[256]) {
    int wave = threadIdx.x >> 6, lane = threadIdx.x & 63;
    int base = (blk * 8 + wave) * 4;
    float acc[4][2] = {{0.f,0.f},{0.f,0.f},{0.f,0.f},{0.f,0.f}};
    stage_Bt(Wl_d, Bt, threadIdx.x);
    __syncthreads();
    gather_rows(xpb, rp_re, col_re, 1.75f, base, N_USER, lane, Atw[wave]);
    kloop_dot2(Atw[wave], Bt, lane, acc);
    __syncthreads();
    stage_Bt(Wl_a, Bt, threadIdx.x);
    __syncthreads();
    gather_rows(xpb, rp_fb, col_fb, 0.7f, base, N_USER, lane, Atw[wave]);
    kloop_dot2(Atw[wave], Bt, lane, acc);
    __syncthreads();
    stage_Bt(Wl_s, Bt, threadIdx.x);
    __syncthreads();
    gather_rows(xub, rp_soc, col_soc, 0.3f, base, N_USER, lane, Atw[wave]);
    kloop_dot2(Atw[wave], Bt, lane, acc);
    __syncthreads();
    stage_Bt_comb(WrD, WrA, WrS, Bt, threadIdx.x);
    __syncthreads();
    load_rows(xub, base, N_USER, lane, Atw[wave]);
    kloop_dot2(Atw[wave], Bt, lane, acc);
    float bc0 = 1.75f*bD[lane]    + 0.7f*bA[lane]    + 0.3f*bS[lane];
    float bc1 = 1.75f*bD[lane+64] + 0.7f*bA[lane+64] + 0.3f*bS[lane+64];
#pragma unroll
    for (int i = 0; i < 4; ++i) {
        int row = base + i;
        if (row < N_USER) {
            out[(size_t)row * DD + lane]      = fmaxf(acc[i][0] + bc0, 0.f);
            out[(size_t)row * DD + lane + 64] = fmaxf(acc[i][1] + bc1, 0.f);
        }
    }
}

__device__ void post_body(
        int blk, const unsigned int* __restrict__ xub,
        const int* __restrict__ rp, const int* __restrict__ col,
        const unsigned int* __restrict__ xpb,
        const float* __restrict__ Wl, const float* __restrict__ Wr,
        const float* __restrict__ bias, float* __restrict__ out,
        unsigned int* Bt, unsigned int (*Atw)[256]) {
    int wave = threadIdx.x >> 6, lane = threadIdx.x & 63;
    int base = (blk * 8 + wave) * 4;
    float acc[4][2] = {{0.f,0.f},{0.f,0.f},{0.f,0.f},{0.f,0.f}};
    stage_Bt(Wl, Bt, threadIdx.x);
    __syncthreads();
    gather_rows(xub, rp, col, 1.0f, base, N_POST, lane, Atw[wave]);
    kloop_dot2(Atw[wave], Bt, lane, acc);
    __syncthreads();
    stage_Bt(Wr, Bt, threadIdx.x);
    __syncthreads();
    load_rows(xpb, base, N_POST, lane, Atw[wave]);
    kloop_dot2(Atw[wave], Bt, lane, acc);
    float b0 = bias[lane], b1 = bias[lane + 64];
#pragma unroll
    for (int i = 0; i < 4; ++i) {
        int row = base + i;
        if (row < N_POST) {
            out[(size_t)row * DD + lane]      = fmaxf(acc[i][0] + b0, 0.f);
            out[(size_t)row * DD + lane + 64] = fmaxf(acc[i][1] + b1, 0.f);
        }
    }
}

// user blocks [0, GU), post blocks [GU, GU+GP)
__global__ __launch_bounds__(512) void main_fused_kernel(
        const unsigned int* __restrict__ xub, const unsigned int* __restrict__ xpb,
        const int* __restrict__ rp_re, const int* __restrict__ col_re,
        const int* __restrict__ rp_fb, const int* __restrict__ col_fb,
        const int* __restrict__ rp_soc, const int* __restrict__ col_soc,
        const int* __restrict__ rp_post, const int* __restrict__ col_post,
        const float* __restrict__ Wl_d, const float* __restrict__ Wl_a,
        const float* __restrict__ Wl_s, const float* __restrict__ WrD,
        const float* __restrict__ WrA, const float* __restrict__ WrS,
        const float* __restrict__ bD, const float* __restrict__ bA,
        const float* __restrict__ bS, const float* __restrict__ Wl_p,
        const float* __restrict__ Wr_p, const float* __restrict__ bl_p,
        float* __restrict__ out_user, float* __restrict__ out_post) {
    __shared__ unsigned int Bt[64 * 128];        // 32 KB
    __shared__ unsigned int Atw[8][256];         // 8 KB -> 40 KB, 4 blk/CU
    if (blockIdx.x < GU) {
        user_body(blockIdx.x, xub, xpb, rp_re, col_re, rp_fb, col_fb,
                  rp_soc, col_soc, Wl_d, Wl_a, Wl_s, WrD, WrA, WrS,
                  bD, bA, bS, out_user, Bt, Atw);
    } else {
        post_body(blockIdx.x - GU, xub, rp_post, col_post, xpb,
                  Wl_p, Wr_p, bl_p, out_post, Bt, Atw);
    }
}

// ------------------------------------------------------------------ launch --
extern "C" void kernel_launch(void* const* d_in, const int* in_sizes, int n_in,
                              void* d_out, int out_size, void* d_ws, size_t ws_size,
                              hipStream_t stream) {
    const float* x_user  = (const float*)d_in[0];
    const float* x_post  = (const float*)d_in[1];
    const int*   re_src  = (const int*)d_in[2];
    const int*   re_dst  = (const int*)d_in[3];
    const int*   fb_src  = (const int*)d_in[4];
    const int*   fb_dst  = (const int*)d_in[5];
    const int*   soc_src = (const int*)d_in[6];
    const int*   soc_dst = (const int*)d_in[7];
    const int*   eng_src = (const int*)d_in[8];
    const int*   eng_dst = (const int*)d_in[9];
    const float* Wl_d = (const float*)d_in[10];
    const float* bl_d = (const float*)d_in[11];
    const float* Wr_d = (const float*)d_in[12];
    const float* Wl_a = (const float*)d_in[13];
    const float* bl_a = (const float*)d_in[14];
    const float* Wr_a = (const float*)d_in[15];
    const float* Wl_s = (const float*)d_in[16];
    const float* bl_s = (const float*)d_in[17];
    const float* Wr_s = (const float*)d_in[18];
    const float* Wl_p = (const float*)d_in[19];
    const float* bl_p = (const float*)d_in[20];
    const float* Wr_p = (const float*)d_in[21];

    const int E_re  = in_sizes[2];
    const int E_fb  = in_sizes[4];
    const int E_soc = in_sizes[6];
    const int E_eng = in_sizes[8];

    int* ib = (int*)d_ws;
    int* rp_re    = ib;
    int* rp_fb    = rp_re   + (N_USER + 1);
    int* rp_soc   = rp_fb   + (N_USER + 1);
    int* rp_post  = rp_soc  + (N_USER + 1);
    int* wcur_re  = rp_post + (N_POST + 1);
    int* wcur_fb  = wcur_re + N_USER;
    int* wcur_soc = wcur_fb + N_USER;
    int* wcur_post= wcur_soc+ N_USER;
    int* psum     = wcur_post + N_POST;      // 4 x 64 slices
    int* col_re   = psum + 256;
    int* col_fb   = col_re  + E_re;
    int* col_soc  = col_fb  + E_fb;
    int* col_post = col_soc + E_soc;
    unsigned int* xub = (unsigned int*)(col_post + E_eng);      // 6.4M uints
    unsigned int* xpb = xub + (size_t)N_USER * 64;              // 12.8M uints

    float* out_user = (float*)d_out;
    float* out_post = out_user + (size_t)N_USER * DD;

    // one memset over rp + wcur + psum (contiguous)
    size_t zero_ints = (size_t)(N_USER + 1) * 3 + (N_POST + 1)
                     + (size_t)N_USER * 3 + N_POST + 256;
    hipMemsetAsync(rp_re, 0, zero_ints * sizeof(int), stream);

    // merged: bf16 feature conversion + 4-relation histogram
    prep_all<<<2048, 256, 0, stream>>>(x_user, x_post, xub, xpb,
                                       re_dst, E_re, rp_re,
                                       fb_dst, E_fb, rp_fb,
                                       soc_dst, E_soc, rp_soc,
                                       eng_dst, E_eng, rp_post);

    const int SC_BLOCKS_ALL = 3 * NBU + NBP;   // 124
    scan_partial_all<<<SC_BLOCKS_ALL, SCB, 0, stream>>>(rp_re, rp_fb, rp_soc,
                                                        rp_post, psum);
    scan_psum_all<<<4, 1024, 0, stream>>>(psum);
    scan_final_all<<<SC_BLOCKS_ALL, SCB, 0, stream>>>(rp_re, rp_fb, rp_soc,
                                                      rp_post, psum,
                                                      E_re, E_fb, E_soc, E_eng);

    fill_all<<<2048, 256, 0, stream>>>(
        re_src,  re_dst,  E_re,  rp_re,   wcur_re,   col_re,
        fb_src,  fb_dst,  E_fb,  rp_fb,   wcur_fb,   col_fb,
        soc_src, soc_dst, E_soc, rp_soc,  wcur_soc,  col_soc,
        eng_src, eng_dst, E_eng, rp_post, wcur_post, col_post);

    main_fused_kernel<<<GU + GP, 512, 0, stream>>>(
        xub, xpb, rp_re, col_re, rp_fb, col_fb, rp_soc, col_soc,
        rp_post, col_post, Wl_d, Wl_a, Wl_s, Wr_d, Wr_a, Wr_s,
        bl_d, bl_a, bl_s, Wl_p, Wr_p, bl_p, out_user, out_post);
}